// Round 1
// baseline (928.151 us; speedup 1.0000x reference)
//
#include <hip/hip_runtime.h>
#include <cstdint>
#include <cstddef>

// ---------------------------------------------------------------------------
// FCAGAT: 3x GATConv (H=2, C=64) + ELU + concat + MLP(384->128->1)
// Strategy: per category:
//   K1 gemm_xw     : xw = x @ W            [N,K]@[K,128] fp32 tiled GEMM
//   K2 att_dots    : a_src/a_dst[n,h] = <xw[n,h,:], att>   (wave per node)
//   K3 zero2+hist  : degree histogram over dst (+1 self loop added in scan)
//   K4 scan_*      : exclusive prefix sum -> CSR offsets
//   K5 fill_adj    : scatter src ids into CSR adjacency (incl. self loops)
//   K6 aggregate   : wave per dst node: online softmax (wave-uniform) then
//                    weighted gather of xw[src] -> agg[dst]   (NO big atomics)
// then final_mlp   : Hcat=elu(agg_i+bias_i); relu(Hcat@Wc1+bc1)@Wc2+bc2
// ---------------------------------------------------------------------------

__device__ __forceinline__ float lrelu02(float x) { return x > 0.f ? x : 0.2f * x; }
__device__ __forceinline__ float elu1(float x) { return x > 0.f ? x : (__expf(x) - 1.f); }

// ---------------- K1: XW = X[M,K] @ W[K,128] ----------------
#define TM 64
#define TN 128
#define TKK 32
__global__ __launch_bounds__(256) void gemm_xw(
    const float* __restrict__ X, const float* __restrict__ W,
    float* __restrict__ XW, int M, int K) {
  __shared__ __align__(16) float xs[TKK][TM];   // transposed x tile
  __shared__ __align__(16) float ws[TKK][TN];
  const int tid = threadIdx.x;
  const int tx = tid & 15;        // col group -> cols tx*8..+7
  const int ty = tid >> 4;        // row group -> rows ty*4..+3
  const int row0 = blockIdx.x * TM;
  float acc[4][8];
#pragma unroll
  for (int r = 0; r < 4; ++r)
#pragma unroll
    for (int c = 0; c < 8; ++c) acc[r][c] = 0.f;

  const int lr = tid >> 2;        // 0..63 : x row within tile
  const int lk = (tid & 3) * 8;   // x k offset
  const int wr = tid >> 3;        // 0..31 : W k row
  const int wc = (tid & 7) * 16;  // W col offset

  for (int k0 = 0; k0 < K; k0 += TKK) {
    int xrow = row0 + lr; if (xrow >= M) xrow = M - 1;   // clamp (loads only)
    const float4* xp = (const float4*)(X + (size_t)xrow * K + k0 + lk);
    float4 xa = xp[0];
    float4 xb = xp[1];
    const float4* wp = (const float4*)(W + (size_t)(k0 + wr) * TN + wc);
    float4 w0 = wp[0], w1 = wp[1], w2 = wp[2], w3 = wp[3];
    __syncthreads();
    xs[lk + 0][lr] = xa.x; xs[lk + 1][lr] = xa.y; xs[lk + 2][lr] = xa.z; xs[lk + 3][lr] = xa.w;
    xs[lk + 4][lr] = xb.x; xs[lk + 5][lr] = xb.y; xs[lk + 6][lr] = xb.z; xs[lk + 7][lr] = xb.w;
    *(float4*)&ws[wr][wc + 0]  = w0;
    *(float4*)&ws[wr][wc + 4]  = w1;
    *(float4*)&ws[wr][wc + 8]  = w2;
    *(float4*)&ws[wr][wc + 12] = w3;
    __syncthreads();
#pragma unroll
    for (int k = 0; k < TKK; ++k) {
      float4 a = *(const float4*)&xs[k][ty * 4];
      float4 b0 = *(const float4*)&ws[k][tx * 8];
      float4 b1 = *(const float4*)&ws[k][tx * 8 + 4];
      float av[4] = {a.x, a.y, a.z, a.w};
      float bv[8] = {b0.x, b0.y, b0.z, b0.w, b1.x, b1.y, b1.z, b1.w};
#pragma unroll
      for (int r = 0; r < 4; ++r)
#pragma unroll
        for (int c = 0; c < 8; ++c)
          acc[r][c] = fmaf(av[r], bv[c], acc[r][c]);
    }
  }
#pragma unroll
  for (int r = 0; r < 4; ++r) {
    int row = row0 + ty * 4 + r;
    if (row < M) {
      float4 o0 = {acc[r][0], acc[r][1], acc[r][2], acc[r][3]};
      float4 o1 = {acc[r][4], acc[r][5], acc[r][6], acc[r][7]};
      float4* op = (float4*)(XW + (size_t)row * TN + tx * 8);
      op[0] = o0; op[1] = o1;
    }
  }
}

// ---------------- K2: attention dots, wave per node ----------------
__global__ __launch_bounds__(256) void att_dots(
    const float* __restrict__ xw, const float* __restrict__ att_s,
    const float* __restrict__ att_d, float* __restrict__ a_src,
    float* __restrict__ a_dst, int Nn) {
  int wave = (int)((blockIdx.x * (size_t)blockDim.x + threadIdx.x) >> 6);
  int lane = threadIdx.x & 63;
  if (wave >= Nn) return;
  float x0 = xw[(size_t)wave * 128 + lane];
  float x1 = xw[(size_t)wave * 128 + 64 + lane];
  float s0 = x0 * att_s[lane];
  float s1 = x1 * att_s[64 + lane];
  float d0 = x0 * att_d[lane];
  float d1 = x1 * att_d[64 + lane];
#pragma unroll
  for (int off = 32; off; off >>= 1) {
    s0 += __shfl_xor(s0, off);
    s1 += __shfl_xor(s1, off);
    d0 += __shfl_xor(d0, off);
    d1 += __shfl_xor(d1, off);
  }
  if (lane == 0) {
    a_src[wave * 2 + 0] = s0;
    a_src[wave * 2 + 1] = s1;
    a_dst[wave * 2 + 0] = d0;
    a_dst[wave * 2 + 1] = d1;
  }
}

// ---------------- K3: zero + degree histogram ----------------
__global__ void zero2(int* __restrict__ a, int* __restrict__ b, int Nn) {
  int i = blockIdx.x * blockDim.x + threadIdx.x;
  if (i < Nn) { a[i] = 0; b[i] = 0; }
}

__global__ void hist_deg(const int* __restrict__ dst, int E, int* __restrict__ deg) {
  int i = blockIdx.x * blockDim.x + threadIdx.x;
  if (i < E) atomicAdd(&deg[dst[i]], 1);
}

// ---------------- K4: 3-phase exclusive scan of (deg[i]+1) ----------------
__global__ __launch_bounds__(1024) void scan_reduce(
    const int* __restrict__ deg, int Nn, int* __restrict__ bsum) {
  __shared__ int wsum[16];
  int tid = threadIdx.x;
  int gi = blockIdx.x * 1024 + tid;
  int x = (gi < Nn) ? (deg[gi] + 1) : 0;
#pragma unroll
  for (int off = 32; off; off >>= 1) x += __shfl_xor(x, off);
  int lane = tid & 63, wid = tid >> 6;
  if (lane == 0) wsum[wid] = x;
  __syncthreads();
  if (tid == 0) {
    int s = 0;
#pragma unroll
    for (int i = 0; i < 16; ++i) s += wsum[i];
    bsum[blockIdx.x] = s;
  }
}

__global__ void scan_tops(const int* __restrict__ bsum, int nb, int* __restrict__ boff) {
  int lane = threadIdx.x;   // 64 threads
  int v = (lane < nb) ? bsum[lane] : 0;
  int orig = v;
#pragma unroll
  for (int off = 1; off < 64; off <<= 1) {
    int t = __shfl_up(v, off);
    if (lane >= off) v += t;
  }
  if (lane < nb) boff[lane] = v - orig;   // exclusive
}

__global__ __launch_bounds__(1024) void scan_final(
    const int* __restrict__ deg, int Nn, const int* __restrict__ boff,
    int* __restrict__ offs) {
  __shared__ int wsum[16];
  int tid = threadIdx.x;
  int gi = blockIdx.x * 1024 + tid;
  int x = (gi < Nn) ? (deg[gi] + 1) : 0;
  int lane = tid & 63, wid = tid >> 6;
  int v = x;
#pragma unroll
  for (int off = 1; off < 64; off <<= 1) {
    int t = __shfl_up(v, off);
    if (lane >= off) v += t;
  }
  if (lane == 63) wsum[wid] = v;
  __syncthreads();
  if (wid == 0) {
    int wv = (lane < 16) ? wsum[lane] : 0;
#pragma unroll
    for (int off = 1; off < 16; off <<= 1) {
      int t = __shfl_up(wv, off);
      if (lane >= off) wv += t;
    }
    if (lane < 16) wsum[lane] = wv;   // inclusive wave sums
  }
  __syncthreads();
  int pre = (wid > 0 ? wsum[wid - 1] : 0) + boff[blockIdx.x];
  if (gi < Nn) offs[gi + 1] = pre + v;
  if (gi == 0) offs[0] = 0;
}

// ---------------- K5: fill CSR adjacency (edges + self loops) ----------------
__global__ void fill_adj(const int* __restrict__ src, const int* __restrict__ dst,
                         int E, int Nn, const int* __restrict__ offs,
                         int* __restrict__ fill, int* __restrict__ adj) {
  int i = blockIdx.x * blockDim.x + threadIdx.x;
  int tot = E + Nn;
  if (i >= tot) return;
  int s, d;
  if (i < E) { s = src[i]; d = dst[i]; }
  else { s = i - E; d = i - E; }
  int p = offs[d] + atomicAdd(&fill[d], 1);
  adj[p] = s;
}

// ---------------- K6: segment softmax + weighted gather, wave per dst ----------------
__global__ __launch_bounds__(256) void aggregate(
    const float* __restrict__ xw, const float* __restrict__ a_src,
    const float* __restrict__ a_dst, const int* __restrict__ offs,
    const int* __restrict__ adj, float* __restrict__ agg, int Nn) {
  int wave = (int)((blockIdx.x * (size_t)blockDim.x + threadIdx.x) >> 6);
  int lane = threadIdx.x & 63;
  if (wave >= Nn) return;
  const int dstn = wave;
  const int base = offs[dstn], end = offs[dstn + 1];
  const float ad0 = a_dst[dstn * 2 + 0];
  const float ad1 = a_dst[dstn * 2 + 1];
  // phase 1: wave-uniform online softmax stats (all lanes compute identically)
  float m0 = -1e30f, s0 = 0.f, m1 = -1e30f, s1 = 0.f;
  for (int j = base; j < end; ++j) {
    int src = adj[j];
    float as0 = a_src[src * 2 + 0];
    float as1 = a_src[src * 2 + 1];
    float e0 = lrelu02(as0 + ad0);
    float e1 = lrelu02(as1 + ad1);
    float nm0 = fmaxf(m0, e0);
    s0 = s0 * __expf(m0 - nm0) + __expf(e0 - nm0); m0 = nm0;
    float nm1 = fmaxf(m1, e1);
    s1 = s1 * __expf(m1 - nm1) + __expf(e1 - nm1); m1 = nm1;
  }
  const float inv0 = 1.f / s0, inv1 = 1.f / s1;
  // phase 2: weighted gather
  float acc0 = 0.f, acc1 = 0.f;
  for (int j = base; j < end; ++j) {
    int src = adj[j];
    float as0 = a_src[src * 2 + 0];
    float as1 = a_src[src * 2 + 1];
    float e0 = lrelu02(as0 + ad0);
    float e1 = lrelu02(as1 + ad1);
    float w0 = __expf(e0 - m0) * inv0;
    float w1 = __expf(e1 - m1) * inv1;
    acc0 = fmaf(w0, xw[(size_t)src * 128 + lane], acc0);
    acc1 = fmaf(w1, xw[(size_t)src * 128 + 64 + lane], acc1);
  }
  agg[(size_t)dstn * 128 + lane] = acc0;
  agg[(size_t)dstn * 128 + 64 + lane] = acc1;
}

// ---------------- K7: final MLP, 32 nodes per block ----------------
#define GNODES 32
__global__ __launch_bounds__(128) void final_mlp(
    const float* __restrict__ agg0, const float* __restrict__ agg1,
    const float* __restrict__ agg2, const float* __restrict__ bias0,
    const float* __restrict__ bias1, const float* __restrict__ bias2,
    const float* __restrict__ Wc1, const float* __restrict__ bc1,
    const float* __restrict__ Wc2, const float* __restrict__ bc2,
    float* __restrict__ out, int Nn) {
  __shared__ __align__(16) float Hs[GNODES][388];
  const int tid = threadIdx.x;   // 128 threads
  const int n0 = blockIdx.x * GNODES;
  const float b0v = bias0[tid], b1v = bias1[tid], b2v = bias2[tid];
#pragma unroll 4
  for (int g = 0; g < GNODES; ++g) {
    int n = n0 + g; if (n >= Nn) n = Nn - 1;
    Hs[g][tid]       = elu1(agg0[(size_t)n * 128 + tid] + b0v);
    Hs[g][128 + tid] = elu1(agg1[(size_t)n * 128 + tid] + b1v);
    Hs[g][256 + tid] = elu1(agg2[(size_t)n * 128 + tid] + b2v);
  }
  __syncthreads();
  const int lane = tid & 63;
  const int grp = tid >> 6;          // wave id: 0 -> nodes 0..15, 1 -> 16..31
  const int gbase = grp * 16;
  const int c0 = lane, c1 = lane + 64;
  float h0[16], h1[16];
  const float bc10 = bc1[c0], bc11 = bc1[c1];
#pragma unroll
  for (int g = 0; g < 16; ++g) { h0[g] = bc10; h1[g] = bc11; }
  for (int kk = 0; kk < 384; kk += 4) {
    float w0[4], w1[4];
#pragma unroll
    for (int u = 0; u < 4; ++u) {
      w0[u] = Wc1[(size_t)(kk + u) * 128 + c0];
      w1[u] = Wc1[(size_t)(kk + u) * 128 + c1];
    }
#pragma unroll
    for (int g = 0; g < 16; ++g) {
      float4 a = *(const float4*)&Hs[gbase + g][kk];
      h0[g] = fmaf(a.x, w0[0], h0[g]);
      h0[g] = fmaf(a.y, w0[1], h0[g]);
      h0[g] = fmaf(a.z, w0[2], h0[g]);
      h0[g] = fmaf(a.w, w0[3], h0[g]);
      h1[g] = fmaf(a.x, w1[0], h1[g]);
      h1[g] = fmaf(a.y, w1[1], h1[g]);
      h1[g] = fmaf(a.z, w1[2], h1[g]);
      h1[g] = fmaf(a.w, w1[3], h1[g]);
    }
  }
  const float wc2a = Wc2[c0], wc2b = Wc2[c1];
  const float bout = bc2[0];
#pragma unroll
  for (int g = 0; g < 16; ++g) {
    float p = fmaxf(h0[g], 0.f) * wc2a + fmaxf(h1[g], 0.f) * wc2b;
#pragma unroll
    for (int off = 32; off; off >>= 1) p += __shfl_xor(p, off);
    if (lane == 0) {
      int n = n0 + gbase + g;
      if (n < Nn) out[n] = p + bout;
    }
  }
}

// ---------------------------------------------------------------------------
extern "C" void kernel_launch(void* const* d_in, const int* in_sizes, int n_in,
                              void* d_out, int out_size, void* d_ws, size_t ws_size,
                              hipStream_t stream) {
  const int Nn = out_size;          // 40000
  const int E  = in_sizes[1] / 2;   // 600000

  // workspace carve (reused across categories except agg[])
  char* base = (char*)d_ws;
  size_t off = 0;
  auto carve = [&](size_t bytes) -> void* {
    off = (off + 255) & ~(size_t)255;
    void* p = base + off;
    off += bytes;
    return p;
  };
  float* xw = (float*)carve((size_t)Nn * 128 * 4);
  float* agg[3];
  for (int i = 0; i < 3; ++i) agg[i] = (float*)carve((size_t)Nn * 128 * 4);
  float* a_src = (float*)carve((size_t)Nn * 2 * 4);
  float* a_dst = (float*)carve((size_t)Nn * 2 * 4);
  int* deg  = (int*)carve((size_t)Nn * 4);
  int* offs = (int*)carve((size_t)(Nn + 1) * 4);
  int* bsum = (int*)carve(64 * 4);
  int* boff = (int*)carve(64 * 4);
  int* fill = (int*)carve((size_t)Nn * 4);
  int* adj  = (int*)carve((size_t)(E + Nn) * 4);
  (void)ws_size; (void)n_in;

  const int nscan = (Nn + 1023) / 1024;

  for (int cat = 0; cat < 3; ++cat) {
    const float* x   = (const float*)d_in[6 * cat + 0];
    const int*   ei  = (const int*)  d_in[6 * cat + 1];
    const float* W   = (const float*)d_in[6 * cat + 2];
    const float* ats = (const float*)d_in[6 * cat + 3];
    const float* atd = (const float*)d_in[6 * cat + 4];
    const int K = in_sizes[6 * cat] / Nn;

    gemm_xw<<<(Nn + TM - 1) / TM, 256, 0, stream>>>(x, W, xw, Nn, K);
    att_dots<<<((size_t)Nn * 64 + 255) / 256, 256, 0, stream>>>(xw, ats, atd, a_src, a_dst, Nn);
    zero2<<<(Nn + 255) / 256, 256, 0, stream>>>(deg, fill, Nn);
    hist_deg<<<(E + 255) / 256, 256, 0, stream>>>(ei + E, E, deg);
    scan_reduce<<<nscan, 1024, 0, stream>>>(deg, Nn, bsum);
    scan_tops<<<1, 64, 0, stream>>>(bsum, nscan, boff);
    scan_final<<<nscan, 1024, 0, stream>>>(deg, Nn, boff, offs);
    fill_adj<<<(E + Nn + 255) / 256, 256, 0, stream>>>(ei, ei + E, E, Nn, offs, fill, adj);
    aggregate<<<((size_t)Nn * 64 + 255) / 256, 256, 0, stream>>>(xw, a_src, a_dst, offs, adj, agg[cat], Nn);
  }

  final_mlp<<<(Nn + GNODES - 1) / GNODES, 128, 0, stream>>>(
      agg[0], agg[1], agg[2],
      (const float*)d_in[5], (const float*)d_in[11], (const float*)d_in[17],
      (const float*)d_in[18], (const float*)d_in[19],
      (const float*)d_in[20], (const float*)d_in[21],
      (float*)d_out, Nn);
}

// Round 2
// 692.069 us; speedup vs baseline: 1.3411x; 1.3411x over previous
//
#include <hip/hip_runtime.h>
#include <cstdint>
#include <cstddef>

// ---------------------------------------------------------------------------
// FCAGAT: 3x GATConv (H=2, C=64) + ELU + concat + MLP(384->128->1)
//   K1 gemm_xw     : xw = x @ W            [N,K]@[K,128] fp32 tiled GEMM
//   K2 att_dots    : a_src/a_dst[n,h] = <xw[n,h,:], att>   (wave per node)
//   K3 zero2+hist  : degree histogram over dst
//   K4 scan_*      : exclusive prefix sum -> CSR offsets
//   K5 fill_adj    : scatter src ids + PRE-COMPUTED logits (e0,e1) into CSR
//   K6 aggregate   : wave per dst: lane-parallel softmax stats (shfl butterfly)
//                    + chunked weighted gather (weights exp'd once per edge)
//   K7 final_mlp   : Hcat=elu(agg_i+bias_i); relu(Hcat@Wc1+bc1)@Wc2+bc2
// ---------------------------------------------------------------------------

__device__ __forceinline__ float lrelu02(float x) { return x > 0.f ? x : 0.2f * x; }
__device__ __forceinline__ float elu1(float x) { return x > 0.f ? x : (__expf(x) - 1.f); }

// ---------------- K1: XW = X[M,K] @ W[K,128] ----------------
#define TM 64
#define TN 128
#define TKK 32
__global__ __launch_bounds__(256) void gemm_xw(
    const float* __restrict__ X, const float* __restrict__ W,
    float* __restrict__ XW, int M, int K) {
  __shared__ __align__(16) float xs[TKK][TM];   // transposed x tile
  __shared__ __align__(16) float ws[TKK][TN];
  const int tid = threadIdx.x;
  const int tx = tid & 15;        // col group -> cols tx*8..+7
  const int ty = tid >> 4;        // row group -> rows ty*4..+3
  const int row0 = blockIdx.x * TM;
  float acc[4][8];
#pragma unroll
  for (int r = 0; r < 4; ++r)
#pragma unroll
    for (int c = 0; c < 8; ++c) acc[r][c] = 0.f;

  const int lr = tid >> 2;        // 0..63 : x row within tile
  const int lk = (tid & 3) * 8;   // x k offset
  const int wr = tid >> 3;        // 0..31 : W k row
  const int wc = (tid & 7) * 16;  // W col offset

  for (int k0 = 0; k0 < K; k0 += TKK) {
    int xrow = row0 + lr; if (xrow >= M) xrow = M - 1;   // clamp (loads only)
    const float4* xp = (const float4*)(X + (size_t)xrow * K + k0 + lk);
    float4 xa = xp[0];
    float4 xb = xp[1];
    const float4* wp = (const float4*)(W + (size_t)(k0 + wr) * TN + wc);
    float4 w0 = wp[0], w1 = wp[1], w2 = wp[2], w3 = wp[3];
    __syncthreads();
    xs[lk + 0][lr] = xa.x; xs[lk + 1][lr] = xa.y; xs[lk + 2][lr] = xa.z; xs[lk + 3][lr] = xa.w;
    xs[lk + 4][lr] = xb.x; xs[lk + 5][lr] = xb.y; xs[lk + 6][lr] = xb.z; xs[lk + 7][lr] = xb.w;
    *(float4*)&ws[wr][wc + 0]  = w0;
    *(float4*)&ws[wr][wc + 4]  = w1;
    *(float4*)&ws[wr][wc + 8]  = w2;
    *(float4*)&ws[wr][wc + 12] = w3;
    __syncthreads();
#pragma unroll
    for (int k = 0; k < TKK; ++k) {
      float4 a = *(const float4*)&xs[k][ty * 4];
      float4 b0 = *(const float4*)&ws[k][tx * 8];
      float4 b1 = *(const float4*)&ws[k][tx * 8 + 4];
      float av[4] = {a.x, a.y, a.z, a.w};
      float bv[8] = {b0.x, b0.y, b0.z, b0.w, b1.x, b1.y, b1.z, b1.w};
#pragma unroll
      for (int r = 0; r < 4; ++r)
#pragma unroll
        for (int c = 0; c < 8; ++c)
          acc[r][c] = fmaf(av[r], bv[c], acc[r][c]);
    }
  }
#pragma unroll
  for (int r = 0; r < 4; ++r) {
    int row = row0 + ty * 4 + r;
    if (row < M) {
      float4 o0 = {acc[r][0], acc[r][1], acc[r][2], acc[r][3]};
      float4 o1 = {acc[r][4], acc[r][5], acc[r][6], acc[r][7]};
      float4* op = (float4*)(XW + (size_t)row * TN + tx * 8);
      op[0] = o0; op[1] = o1;
    }
  }
}

// ---------------- K2: attention dots, wave per node ----------------
__global__ __launch_bounds__(256) void att_dots(
    const float* __restrict__ xw, const float* __restrict__ att_s,
    const float* __restrict__ att_d, float* __restrict__ a_src,
    float* __restrict__ a_dst, int Nn) {
  int wave = (int)((blockIdx.x * (size_t)blockDim.x + threadIdx.x) >> 6);
  int lane = threadIdx.x & 63;
  if (wave >= Nn) return;
  float x0 = xw[(size_t)wave * 128 + lane];
  float x1 = xw[(size_t)wave * 128 + 64 + lane];
  float s0 = x0 * att_s[lane];
  float s1 = x1 * att_s[64 + lane];
  float d0 = x0 * att_d[lane];
  float d1 = x1 * att_d[64 + lane];
#pragma unroll
  for (int off = 32; off; off >>= 1) {
    s0 += __shfl_xor(s0, off);
    s1 += __shfl_xor(s1, off);
    d0 += __shfl_xor(d0, off);
    d1 += __shfl_xor(d1, off);
  }
  if (lane == 0) {
    a_src[wave * 2 + 0] = s0;
    a_src[wave * 2 + 1] = s1;
    a_dst[wave * 2 + 0] = d0;
    a_dst[wave * 2 + 1] = d1;
  }
}

// ---------------- K3: zero + degree histogram ----------------
__global__ void zero2(int* __restrict__ a, int* __restrict__ b, int Nn) {
  int i = blockIdx.x * blockDim.x + threadIdx.x;
  if (i < Nn) { a[i] = 0; b[i] = 0; }
}

__global__ void hist_deg(const int* __restrict__ dst, int E, int* __restrict__ deg) {
  int i = blockIdx.x * blockDim.x + threadIdx.x;
  if (i < E) atomicAdd(&deg[dst[i]], 1);
}

// ---------------- K4: 3-phase exclusive scan of (deg[i]+1) ----------------
__global__ __launch_bounds__(1024) void scan_reduce(
    const int* __restrict__ deg, int Nn, int* __restrict__ bsum) {
  __shared__ int wsum[16];
  int tid = threadIdx.x;
  int gi = blockIdx.x * 1024 + tid;
  int x = (gi < Nn) ? (deg[gi] + 1) : 0;
#pragma unroll
  for (int off = 32; off; off >>= 1) x += __shfl_xor(x, off);
  int lane = tid & 63, wid = tid >> 6;
  if (lane == 0) wsum[wid] = x;
  __syncthreads();
  if (tid == 0) {
    int s = 0;
#pragma unroll
    for (int i = 0; i < 16; ++i) s += wsum[i];
    bsum[blockIdx.x] = s;
  }
}

__global__ void scan_tops(const int* __restrict__ bsum, int nb, int* __restrict__ boff) {
  int lane = threadIdx.x;   // 64 threads
  int v = (lane < nb) ? bsum[lane] : 0;
  int orig = v;
#pragma unroll
  for (int off = 1; off < 64; off <<= 1) {
    int t = __shfl_up(v, off);
    if (lane >= off) v += t;
  }
  if (lane < nb) boff[lane] = v - orig;   // exclusive
}

__global__ __launch_bounds__(1024) void scan_final(
    const int* __restrict__ deg, int Nn, const int* __restrict__ boff,
    int* __restrict__ offs) {
  __shared__ int wsum[16];
  int tid = threadIdx.x;
  int gi = blockIdx.x * 1024 + tid;
  int x = (gi < Nn) ? (deg[gi] + 1) : 0;
  int lane = tid & 63, wid = tid >> 6;
  int v = x;
#pragma unroll
  for (int off = 1; off < 64; off <<= 1) {
    int t = __shfl_up(v, off);
    if (lane >= off) v += t;
  }
  if (lane == 63) wsum[wid] = v;
  __syncthreads();
  if (wid == 0) {
    int wv = (lane < 16) ? wsum[lane] : 0;
#pragma unroll
    for (int off = 1; off < 16; off <<= 1) {
      int t = __shfl_up(wv, off);
      if (lane >= off) wv += t;
    }
    if (lane < 16) wsum[lane] = wv;   // inclusive wave sums
  }
  __syncthreads();
  int pre = (wid > 0 ? wsum[wid - 1] : 0) + boff[blockIdx.x];
  if (gi < Nn) offs[gi + 1] = pre + v;
  if (gi == 0) offs[0] = 0;
}

// ---------------- K5: fill CSR adjacency + per-edge logits ----------------
__global__ void fill_adj(const int* __restrict__ src, const int* __restrict__ dst,
                         int E, int Nn, const int* __restrict__ offs,
                         const float* __restrict__ a_src, const float* __restrict__ a_dst,
                         int* __restrict__ fill, int* __restrict__ adj,
                         float2* __restrict__ el) {
  int i = blockIdx.x * blockDim.x + threadIdx.x;
  int tot = E + Nn;
  if (i >= tot) return;
  int s, d;
  if (i < E) { s = src[i]; d = dst[i]; }
  else { s = i - E; d = i - E; }
  int p = offs[d] + atomicAdd(&fill[d], 1);
  adj[p] = s;
  float e0 = lrelu02(a_src[s * 2 + 0] + a_dst[d * 2 + 0]);
  float e1 = lrelu02(a_src[s * 2 + 1] + a_dst[d * 2 + 1]);
  el[p] = make_float2(e0, e1);
}

// ---------------- K6: lane-parallel segment softmax + chunked gather ----------------
__global__ __launch_bounds__(256) void aggregate(
    const float* __restrict__ xw, const int* __restrict__ offs,
    const int* __restrict__ adj, const float2* __restrict__ el,
    float* __restrict__ agg, int Nn) {
  const int wave = (int)((blockIdx.x * (size_t)blockDim.x + threadIdx.x) >> 6);
  const int lane = threadIdx.x & 63;
  if (wave >= Nn) return;
  const int base = offs[wave], end = offs[wave + 1];

  // phase 1: lane-strided online softmax stats, then butterfly merge
  float m0 = -1e30f, s0 = 0.f, m1 = -1e30f, s1 = 0.f;
  for (int j = base + lane; j < end; j += 64) {
    float2 e = el[j];
    float nm0 = fmaxf(m0, e.x);
    s0 = s0 * __expf(m0 - nm0) + __expf(e.x - nm0); m0 = nm0;
    float nm1 = fmaxf(m1, e.y);
    s1 = s1 * __expf(m1 - nm1) + __expf(e.y - nm1); m1 = nm1;
  }
#pragma unroll
  for (int off = 32; off; off >>= 1) {
    float om0 = __shfl_xor(m0, off), os0 = __shfl_xor(s0, off);
    float nm0 = fmaxf(m0, om0);
    s0 = s0 * __expf(m0 - nm0) + os0 * __expf(om0 - nm0); m0 = nm0;
    float om1 = __shfl_xor(m1, off), os1 = __shfl_xor(s1, off);
    float nm1 = fmaxf(m1, om1);
    s1 = s1 * __expf(m1 - nm1) + os1 * __expf(om1 - nm1); m1 = nm1;
  }
  const float inv0 = 1.f / s0, inv1 = 1.f / s1;

  // phase 2: chunks of 64 edges; weight exp'd once per edge (by its lane),
  // then broadcast via shfl; gathers unrolled x4 for memory-level parallelism
  float acc0 = 0.f, acc1 = 0.f;
  for (int cb = base; cb < end; cb += 64) {
    const int cnt = min(64, end - cb);
    int srcv = 0; float w0v = 0.f, w1v = 0.f;
    if (lane < cnt) {
      srcv = adj[cb + lane];
      float2 e = el[cb + lane];
      w0v = __expf(e.x - m0) * inv0;
      w1v = __expf(e.y - m1) * inv1;
    }
    int k = 0;
    for (; k + 4 <= cnt; k += 4) {
      int sa = __shfl(srcv, k),     sb = __shfl(srcv, k + 1);
      int sc = __shfl(srcv, k + 2), sd = __shfl(srcv, k + 3);
      float wa0 = __shfl(w0v, k),     wb0 = __shfl(w0v, k + 1);
      float wc0 = __shfl(w0v, k + 2), wd0 = __shfl(w0v, k + 3);
      float wa1 = __shfl(w1v, k),     wb1 = __shfl(w1v, k + 1);
      float wc1 = __shfl(w1v, k + 2), wd1 = __shfl(w1v, k + 3);
      const float* pa = xw + (size_t)sa * 128 + lane;
      const float* pb = xw + (size_t)sb * 128 + lane;
      const float* pc = xw + (size_t)sc * 128 + lane;
      const float* pd = xw + (size_t)sd * 128 + lane;
      float xa0 = pa[0], xa1 = pa[64];
      float xb0 = pb[0], xb1 = pb[64];
      float xc0 = pc[0], xc1 = pc[64];
      float xd0 = pd[0], xd1 = pd[64];
      acc0 = fmaf(wa0, xa0, acc0); acc1 = fmaf(wa1, xa1, acc1);
      acc0 = fmaf(wb0, xb0, acc0); acc1 = fmaf(wb1, xb1, acc1);
      acc0 = fmaf(wc0, xc0, acc0); acc1 = fmaf(wc1, xc1, acc1);
      acc0 = fmaf(wd0, xd0, acc0); acc1 = fmaf(wd1, xd1, acc1);
    }
    for (; k < cnt; ++k) {
      int s = __shfl(srcv, k);
      float w0 = __shfl(w0v, k);
      float w1 = __shfl(w1v, k);
      const float* p = xw + (size_t)s * 128 + lane;
      acc0 = fmaf(w0, p[0], acc0);
      acc1 = fmaf(w1, p[64], acc1);
    }
  }
  agg[(size_t)wave * 128 + lane] = acc0;
  agg[(size_t)wave * 128 + 64 + lane] = acc1;
}

// ---------------- K7: final MLP, 32 nodes per block ----------------
#define GNODES 32
__global__ __launch_bounds__(128) void final_mlp(
    const float* __restrict__ agg0, const float* __restrict__ agg1,
    const float* __restrict__ agg2, const float* __restrict__ bias0,
    const float* __restrict__ bias1, const float* __restrict__ bias2,
    const float* __restrict__ Wc1, const float* __restrict__ bc1,
    const float* __restrict__ Wc2, const float* __restrict__ bc2,
    float* __restrict__ out, int Nn) {
  __shared__ __align__(16) float Hs[GNODES][388];
  const int tid = threadIdx.x;   // 128 threads
  const int n0 = blockIdx.x * GNODES;
  const float b0v = bias0[tid], b1v = bias1[tid], b2v = bias2[tid];
#pragma unroll 4
  for (int g = 0; g < GNODES; ++g) {
    int n = n0 + g; if (n >= Nn) n = Nn - 1;
    Hs[g][tid]       = elu1(agg0[(size_t)n * 128 + tid] + b0v);
    Hs[g][128 + tid] = elu1(agg1[(size_t)n * 128 + tid] + b1v);
    Hs[g][256 + tid] = elu1(agg2[(size_t)n * 128 + tid] + b2v);
  }
  __syncthreads();
  const int lane = tid & 63;
  const int grp = tid >> 6;          // wave id: 0 -> nodes 0..15, 1 -> 16..31
  const int gbase = grp * 16;
  const int c0 = lane, c1 = lane + 64;
  float h0[16], h1[16];
  const float bc10 = bc1[c0], bc11 = bc1[c1];
#pragma unroll
  for (int g = 0; g < 16; ++g) { h0[g] = bc10; h1[g] = bc11; }
  for (int kk = 0; kk < 384; kk += 4) {
    float w0[4], w1[4];
#pragma unroll
    for (int u = 0; u < 4; ++u) {
      w0[u] = Wc1[(size_t)(kk + u) * 128 + c0];
      w1[u] = Wc1[(size_t)(kk + u) * 128 + c1];
    }
#pragma unroll
    for (int g = 0; g < 16; ++g) {
      float4 a = *(const float4*)&Hs[gbase + g][kk];
      h0[g] = fmaf(a.x, w0[0], h0[g]);
      h0[g] = fmaf(a.y, w0[1], h0[g]);
      h0[g] = fmaf(a.z, w0[2], h0[g]);
      h0[g] = fmaf(a.w, w0[3], h0[g]);
      h1[g] = fmaf(a.x, w1[0], h1[g]);
      h1[g] = fmaf(a.y, w1[1], h1[g]);
      h1[g] = fmaf(a.z, w1[2], h1[g]);
      h1[g] = fmaf(a.w, w1[3], h1[g]);
    }
  }
  const float wc2a = Wc2[c0], wc2b = Wc2[c1];
  const float bout = bc2[0];
#pragma unroll
  for (int g = 0; g < 16; ++g) {
    float p = fmaxf(h0[g], 0.f) * wc2a + fmaxf(h1[g], 0.f) * wc2b;
#pragma unroll
    for (int off = 32; off; off >>= 1) p += __shfl_xor(p, off);
    if (lane == 0) {
      int n = n0 + gbase + g;
      if (n < Nn) out[n] = p + bout;
    }
  }
}

// ---------------------------------------------------------------------------
extern "C" void kernel_launch(void* const* d_in, const int* in_sizes, int n_in,
                              void* d_out, int out_size, void* d_ws, size_t ws_size,
                              hipStream_t stream) {
  const int Nn = out_size;          // 40000
  const int E  = in_sizes[1] / 2;   // 600000

  // workspace carve (reused across categories except agg[])
  char* base = (char*)d_ws;
  size_t off = 0;
  auto carve = [&](size_t bytes) -> void* {
    off = (off + 255) & ~(size_t)255;
    void* p = base + off;
    off += bytes;
    return p;
  };
  float* xw = (float*)carve((size_t)Nn * 128 * 4);
  float* agg[3];
  for (int i = 0; i < 3; ++i) agg[i] = (float*)carve((size_t)Nn * 128 * 4);
  float* a_src = (float*)carve((size_t)Nn * 2 * 4);
  float* a_dst = (float*)carve((size_t)Nn * 2 * 4);
  int* deg  = (int*)carve((size_t)Nn * 4);
  int* offs = (int*)carve((size_t)(Nn + 1) * 4);
  int* bsum = (int*)carve(64 * 4);
  int* boff = (int*)carve(64 * 4);
  int* fill = (int*)carve((size_t)Nn * 4);
  int* adj  = (int*)carve((size_t)(E + Nn) * 4);
  float2* el = (float2*)carve((size_t)(E + Nn) * 8);
  (void)ws_size; (void)n_in;

  const int nscan = (Nn + 1023) / 1024;

  for (int cat = 0; cat < 3; ++cat) {
    const float* x   = (const float*)d_in[6 * cat + 0];
    const int*   ei  = (const int*)  d_in[6 * cat + 1];
    const float* W   = (const float*)d_in[6 * cat + 2];
    const float* ats = (const float*)d_in[6 * cat + 3];
    const float* atd = (const float*)d_in[6 * cat + 4];
    const int K = in_sizes[6 * cat] / Nn;

    gemm_xw<<<(Nn + TM - 1) / TM, 256, 0, stream>>>(x, W, xw, Nn, K);
    att_dots<<<((size_t)Nn * 64 + 255) / 256, 256, 0, stream>>>(xw, ats, atd, a_src, a_dst, Nn);
    zero2<<<(Nn + 255) / 256, 256, 0, stream>>>(deg, fill, Nn);
    hist_deg<<<(E + 255) / 256, 256, 0, stream>>>(ei + E, E, deg);
    scan_reduce<<<nscan, 1024, 0, stream>>>(deg, Nn, bsum);
    scan_tops<<<1, 64, 0, stream>>>(bsum, nscan, boff);
    scan_final<<<nscan, 1024, 0, stream>>>(deg, Nn, boff, offs);
    fill_adj<<<(E + Nn + 255) / 256, 256, 0, stream>>>(ei, ei + E, E, Nn, offs, a_src, a_dst, fill, adj, el);
    aggregate<<<((size_t)Nn * 64 + 255) / 256, 256, 0, stream>>>(xw, offs, adj, el, agg[cat], Nn);
  }

  final_mlp<<<(Nn + GNODES - 1) / GNODES, 128, 0, stream>>>(
      agg[0], agg[1], agg[2],
      (const float*)d_in[5], (const float*)d_in[11], (const float*)d_in[17],
      (const float*)d_in[18], (const float*)d_in[19],
      (const float*)d_in[20], (const float*)d_in[21],
      (float*)d_out, Nn);
}

// Round 3
// 667.539 us; speedup vs baseline: 1.3904x; 1.0367x over previous
//
#include <hip/hip_runtime.h>
#include <cstdint>
#include <cstddef>

// ---------------------------------------------------------------------------
// FCAGAT: 3x GATConv (H=2, C=64) + ELU + concat + MLP(384->128->1)
//   K1 gemm_xw     : xw = x @ W            [N,K]@[K,128] fp32 tiled GEMM
//   K2 att_dots    : a_src/a_dst[n,h] = <xw[n,h,:], att>   (wave per node)
//   K3 zero2+hist  : degree histogram over dst
//   K4 scan_*      : exclusive prefix sum -> CSR offsets
//   K5 fill_adj    : scatter src ids + PRE-COMPUTED logits (e0,e1) into CSR
//   K6 aggregate   : wave per dst: lane-parallel softmax stats (shfl butterfly)
//                    + chunked weighted gather (weights exp'd once per edge)
//   K7 final_mlp   : Hcat=elu(agg_i+bias_i); relu(Hcat@Wc1+bc1)@Wc2+bc2
//                    256 thr / 32 nodes / wave=8 nodes; weight prefetch.
// ---------------------------------------------------------------------------

__device__ __forceinline__ float lrelu02(float x) { return x > 0.f ? x : 0.2f * x; }
__device__ __forceinline__ float elu1(float x) { return x > 0.f ? x : (__expf(x) - 1.f); }

// ---------------- K1: XW = X[M,K] @ W[K,128] ----------------
#define TM 64
#define TN 128
#define TKK 32
__global__ __launch_bounds__(256) void gemm_xw(
    const float* __restrict__ X, const float* __restrict__ W,
    float* __restrict__ XW, int M, int K) {
  __shared__ __align__(16) float xs[TKK][TM];   // transposed x tile
  __shared__ __align__(16) float ws[TKK][TN];
  const int tid = threadIdx.x;
  const int tx = tid & 15;        // col group -> cols tx*8..+7
  const int ty = tid >> 4;        // row group -> rows ty*4..+3
  const int row0 = blockIdx.x * TM;
  float acc[4][8];
#pragma unroll
  for (int r = 0; r < 4; ++r)
#pragma unroll
    for (int c = 0; c < 8; ++c) acc[r][c] = 0.f;

  const int lr = tid >> 2;        // 0..63 : x row within tile
  const int lk = (tid & 3) * 8;   // x k offset
  const int wr = tid >> 3;        // 0..31 : W k row
  const int wc = (tid & 7) * 16;  // W col offset

  for (int k0 = 0; k0 < K; k0 += TKK) {
    int xrow = row0 + lr; if (xrow >= M) xrow = M - 1;   // clamp (loads only)
    const float4* xp = (const float4*)(X + (size_t)xrow * K + k0 + lk);
    float4 xa = xp[0];
    float4 xb = xp[1];
    const float4* wp = (const float4*)(W + (size_t)(k0 + wr) * TN + wc);
    float4 w0 = wp[0], w1 = wp[1], w2 = wp[2], w3 = wp[3];
    __syncthreads();
    xs[lk + 0][lr] = xa.x; xs[lk + 1][lr] = xa.y; xs[lk + 2][lr] = xa.z; xs[lk + 3][lr] = xa.w;
    xs[lk + 4][lr] = xb.x; xs[lk + 5][lr] = xb.y; xs[lk + 6][lr] = xb.z; xs[lk + 7][lr] = xb.w;
    *(float4*)&ws[wr][wc + 0]  = w0;
    *(float4*)&ws[wr][wc + 4]  = w1;
    *(float4*)&ws[wr][wc + 8]  = w2;
    *(float4*)&ws[wr][wc + 12] = w3;
    __syncthreads();
#pragma unroll
    for (int k = 0; k < TKK; ++k) {
      float4 a = *(const float4*)&xs[k][ty * 4];
      float4 b0 = *(const float4*)&ws[k][tx * 8];
      float4 b1 = *(const float4*)&ws[k][tx * 8 + 4];
      float av[4] = {a.x, a.y, a.z, a.w};
      float bv[8] = {b0.x, b0.y, b0.z, b0.w, b1.x, b1.y, b1.z, b1.w};
#pragma unroll
      for (int r = 0; r < 4; ++r)
#pragma unroll
        for (int c = 0; c < 8; ++c)
          acc[r][c] = fmaf(av[r], bv[c], acc[r][c]);
    }
  }
#pragma unroll
  for (int r = 0; r < 4; ++r) {
    int row = row0 + ty * 4 + r;
    if (row < M) {
      float4 o0 = {acc[r][0], acc[r][1], acc[r][2], acc[r][3]};
      float4 o1 = {acc[r][4], acc[r][5], acc[r][6], acc[r][7]};
      float4* op = (float4*)(XW + (size_t)row * TN + tx * 8);
      op[0] = o0; op[1] = o1;
    }
  }
}

// ---------------- K2: attention dots, wave per node ----------------
__global__ __launch_bounds__(256) void att_dots(
    const float* __restrict__ xw, const float* __restrict__ att_s,
    const float* __restrict__ att_d, float* __restrict__ a_src,
    float* __restrict__ a_dst, int Nn) {
  int wave = (int)((blockIdx.x * (size_t)blockDim.x + threadIdx.x) >> 6);
  int lane = threadIdx.x & 63;
  if (wave >= Nn) return;
  float x0 = xw[(size_t)wave * 128 + lane];
  float x1 = xw[(size_t)wave * 128 + 64 + lane];
  float s0 = x0 * att_s[lane];
  float s1 = x1 * att_s[64 + lane];
  float d0 = x0 * att_d[lane];
  float d1 = x1 * att_d[64 + lane];
#pragma unroll
  for (int off = 32; off; off >>= 1) {
    s0 += __shfl_xor(s0, off);
    s1 += __shfl_xor(s1, off);
    d0 += __shfl_xor(d0, off);
    d1 += __shfl_xor(d1, off);
  }
  if (lane == 0) {
    a_src[wave * 2 + 0] = s0;
    a_src[wave * 2 + 1] = s1;
    a_dst[wave * 2 + 0] = d0;
    a_dst[wave * 2 + 1] = d1;
  }
}

// ---------------- K3: zero + degree histogram ----------------
__global__ void zero2(int* __restrict__ a, int* __restrict__ b, int Nn) {
  int i = blockIdx.x * blockDim.x + threadIdx.x;
  if (i < Nn) { a[i] = 0; b[i] = 0; }
}

__global__ void hist_deg(const int* __restrict__ dst, int E, int* __restrict__ deg) {
  int i = blockIdx.x * blockDim.x + threadIdx.x;
  if (i < E) atomicAdd(&deg[dst[i]], 1);
}

// ---------------- K4: 3-phase exclusive scan of (deg[i]+1) ----------------
__global__ __launch_bounds__(1024) void scan_reduce(
    const int* __restrict__ deg, int Nn, int* __restrict__ bsum) {
  __shared__ int wsum[16];
  int tid = threadIdx.x;
  int gi = blockIdx.x * 1024 + tid;
  int x = (gi < Nn) ? (deg[gi] + 1) : 0;
#pragma unroll
  for (int off = 32; off; off >>= 1) x += __shfl_xor(x, off);
  int lane = tid & 63, wid = tid >> 6;
  if (lane == 0) wsum[wid] = x;
  __syncthreads();
  if (tid == 0) {
    int s = 0;
#pragma unroll
    for (int i = 0; i < 16; ++i) s += wsum[i];
    bsum[blockIdx.x] = s;
  }
}

__global__ void scan_tops(const int* __restrict__ bsum, int nb, int* __restrict__ boff) {
  int lane = threadIdx.x;   // 64 threads
  int v = (lane < nb) ? bsum[lane] : 0;
  int orig = v;
#pragma unroll
  for (int off = 1; off < 64; off <<= 1) {
    int t = __shfl_up(v, off);
    if (lane >= off) v += t;
  }
  if (lane < nb) boff[lane] = v - orig;   // exclusive
}

__global__ __launch_bounds__(1024) void scan_final(
    const int* __restrict__ deg, int Nn, const int* __restrict__ boff,
    int* __restrict__ offs) {
  __shared__ int wsum[16];
  int tid = threadIdx.x;
  int gi = blockIdx.x * 1024 + tid;
  int x = (gi < Nn) ? (deg[gi] + 1) : 0;
  int lane = tid & 63, wid = tid >> 6;
  int v = x;
#pragma unroll
  for (int off = 1; off < 64; off <<= 1) {
    int t = __shfl_up(v, off);
    if (lane >= off) v += t;
  }
  if (lane == 63) wsum[wid] = v;
  __syncthreads();
  if (wid == 0) {
    int wv = (lane < 16) ? wsum[lane] : 0;
#pragma unroll
    for (int off = 1; off < 16; off <<= 1) {
      int t = __shfl_up(wv, off);
      if (lane >= off) wv += t;
    }
    if (lane < 16) wsum[lane] = wv;   // inclusive wave sums
  }
  __syncthreads();
  int pre = (wid > 0 ? wsum[wid - 1] : 0) + boff[blockIdx.x];
  if (gi < Nn) offs[gi + 1] = pre + v;
  if (gi == 0) offs[0] = 0;
}

// ---------------- K5: fill CSR adjacency + per-edge logits ----------------
__global__ void fill_adj(const int* __restrict__ src, const int* __restrict__ dst,
                         int E, int Nn, const int* __restrict__ offs,
                         const float* __restrict__ a_src, const float* __restrict__ a_dst,
                         int* __restrict__ fill, int* __restrict__ adj,
                         float2* __restrict__ el) {
  int i = blockIdx.x * blockDim.x + threadIdx.x;
  int tot = E + Nn;
  if (i >= tot) return;
  int s, d;
  if (i < E) { s = src[i]; d = dst[i]; }
  else { s = i - E; d = i - E; }
  int p = offs[d] + atomicAdd(&fill[d], 1);
  adj[p] = s;
  float e0 = lrelu02(a_src[s * 2 + 0] + a_dst[d * 2 + 0]);
  float e1 = lrelu02(a_src[s * 2 + 1] + a_dst[d * 2 + 1]);
  el[p] = make_float2(e0, e1);
}

// ---------------- K6: lane-parallel segment softmax + chunked gather ----------------
__global__ __launch_bounds__(256) void aggregate(
    const float* __restrict__ xw, const int* __restrict__ offs,
    const int* __restrict__ adj, const float2* __restrict__ el,
    float* __restrict__ agg, int Nn) {
  const int wave = (int)((blockIdx.x * (size_t)blockDim.x + threadIdx.x) >> 6);
  const int lane = threadIdx.x & 63;
  if (wave >= Nn) return;
  const int base = offs[wave], end = offs[wave + 1];

  // phase 1: lane-strided online softmax stats, then butterfly merge
  float m0 = -1e30f, s0 = 0.f, m1 = -1e30f, s1 = 0.f;
  for (int j = base + lane; j < end; j += 64) {
    float2 e = el[j];
    float nm0 = fmaxf(m0, e.x);
    s0 = s0 * __expf(m0 - nm0) + __expf(e.x - nm0); m0 = nm0;
    float nm1 = fmaxf(m1, e.y);
    s1 = s1 * __expf(m1 - nm1) + __expf(e.y - nm1); m1 = nm1;
  }
#pragma unroll
  for (int off = 32; off; off >>= 1) {
    float om0 = __shfl_xor(m0, off), os0 = __shfl_xor(s0, off);
    float nm0 = fmaxf(m0, om0);
    s0 = s0 * __expf(m0 - nm0) + os0 * __expf(om0 - nm0); m0 = nm0;
    float om1 = __shfl_xor(m1, off), os1 = __shfl_xor(s1, off);
    float nm1 = fmaxf(m1, om1);
    s1 = s1 * __expf(m1 - nm1) + os1 * __expf(om1 - nm1); m1 = nm1;
  }
  const float inv0 = 1.f / s0, inv1 = 1.f / s1;

  // phase 2: chunks of 64 edges; weight exp'd once per edge (by its lane),
  // then broadcast via shfl; gathers unrolled x4 for memory-level parallelism
  float acc0 = 0.f, acc1 = 0.f;
  for (int cb = base; cb < end; cb += 64) {
    const int cnt = min(64, end - cb);
    int srcv = 0; float w0v = 0.f, w1v = 0.f;
    if (lane < cnt) {
      srcv = adj[cb + lane];
      float2 e = el[cb + lane];
      w0v = __expf(e.x - m0) * inv0;
      w1v = __expf(e.y - m1) * inv1;
    }
    int k = 0;
    for (; k + 4 <= cnt; k += 4) {
      int sa = __shfl(srcv, k),     sb = __shfl(srcv, k + 1);
      int sc = __shfl(srcv, k + 2), sd = __shfl(srcv, k + 3);
      float wa0 = __shfl(w0v, k),     wb0 = __shfl(w0v, k + 1);
      float wc0 = __shfl(w0v, k + 2), wd0 = __shfl(w0v, k + 3);
      float wa1 = __shfl(w1v, k),     wb1 = __shfl(w1v, k + 1);
      float wc1 = __shfl(w1v, k + 2), wd1 = __shfl(w1v, k + 3);
      const float* pa = xw + (size_t)sa * 128 + lane;
      const float* pb = xw + (size_t)sb * 128 + lane;
      const float* pc = xw + (size_t)sc * 128 + lane;
      const float* pd = xw + (size_t)sd * 128 + lane;
      float xa0 = pa[0], xa1 = pa[64];
      float xb0 = pb[0], xb1 = pb[64];
      float xc0 = pc[0], xc1 = pc[64];
      float xd0 = pd[0], xd1 = pd[64];
      acc0 = fmaf(wa0, xa0, acc0); acc1 = fmaf(wa1, xa1, acc1);
      acc0 = fmaf(wb0, xb0, acc0); acc1 = fmaf(wb1, xb1, acc1);
      acc0 = fmaf(wc0, xc0, acc0); acc1 = fmaf(wc1, xc1, acc1);
      acc0 = fmaf(wd0, xd0, acc0); acc1 = fmaf(wd1, xd1, acc1);
    }
    for (; k < cnt; ++k) {
      int s = __shfl(srcv, k);
      float w0 = __shfl(w0v, k);
      float w1 = __shfl(w1v, k);
      const float* p = xw + (size_t)s * 128 + lane;
      acc0 = fmaf(w0, p[0], acc0);
      acc1 = fmaf(w1, p[64], acc1);
    }
  }
  agg[(size_t)wave * 128 + lane] = acc0;
  agg[(size_t)wave * 128 + 64 + lane] = acc1;
}

// ---------------- K7: final MLP, 32 nodes per block, 4 waves ----------------
// 256 thr / 50 KB LDS -> 3 blocks/CU = 12 waves/CU (~37% occ, was 12%).
// Weight chunk for kk+4 prefetched while FMAs run on kk.
#define GNODES 32
__global__ __launch_bounds__(256) void final_mlp(
    const float* __restrict__ agg0, const float* __restrict__ agg1,
    const float* __restrict__ agg2, const float* __restrict__ bias0,
    const float* __restrict__ bias1, const float* __restrict__ bias2,
    const float* __restrict__ Wc1, const float* __restrict__ bc1,
    const float* __restrict__ Wc2, const float* __restrict__ bc2,
    float* __restrict__ out, int Nn) {
  __shared__ __align__(16) float Hs[GNODES][392];   // 392: 16B-aligned rows
  const int tid = threadIdx.x;   // 256 threads
  const int n0 = blockIdx.x * GNODES;

  // ---- stage Hcat = elu(agg + bias) into LDS, float4-vectorized ----
  // 32 nodes * 96 float4 = 3072 slots; 12 per thread; coalesced.
#pragma unroll 4
  for (int i = 0; i < 12; ++i) {
    int slot = tid + 256 * i;
    int node = slot / 96;
    int k = (slot - node * 96) * 4;     // 0..380
    int n = n0 + node; if (n >= Nn) n = Nn - 1;
    const float* srcp; const float* bp; int q;
    if (k < 128)      { srcp = agg0 + (size_t)n * 128; bp = bias0; q = k; }
    else if (k < 256) { srcp = agg1 + (size_t)n * 128; bp = bias1; q = k - 128; }
    else              { srcp = agg2 + (size_t)n * 128; bp = bias2; q = k - 256; }
    float4 v = *(const float4*)(srcp + q);
    float4 b = *(const float4*)(bp + q);
    v.x = elu1(v.x + b.x); v.y = elu1(v.y + b.y);
    v.z = elu1(v.z + b.z); v.w = elu1(v.w + b.w);
    *(float4*)&Hs[node][k] = v;
  }
  __syncthreads();

  const int lane = tid & 63;
  const int wv = tid >> 6;            // wave 0..3 -> nodes wv*8 .. +7
  const int gbase = wv * 8;
  const int c0 = lane, c1 = lane + 64;
  float h0[8], h1[8];
  const float bc10 = bc1[c0], bc11 = bc1[c1];
#pragma unroll
  for (int g = 0; g < 8; ++g) { h0[g] = bc10; h1[g] = bc11; }

  float w0c[4], w1c[4], w0n[4], w1n[4];
#pragma unroll
  for (int u = 0; u < 4; ++u) {
    w0c[u] = Wc1[(size_t)u * 128 + c0];
    w1c[u] = Wc1[(size_t)u * 128 + c1];
  }
  for (int kk = 0; kk < 384; kk += 4) {
    const int kn = kk + 4;
    if (kn < 384) {
#pragma unroll
      for (int u = 0; u < 4; ++u) {
        w0n[u] = Wc1[(size_t)(kn + u) * 128 + c0];
        w1n[u] = Wc1[(size_t)(kn + u) * 128 + c1];
      }
    }
#pragma unroll
    for (int g = 0; g < 8; ++g) {
      float4 a = *(const float4*)&Hs[gbase + g][kk];
      h0[g] = fmaf(a.x, w0c[0], h0[g]);
      h0[g] = fmaf(a.y, w0c[1], h0[g]);
      h0[g] = fmaf(a.z, w0c[2], h0[g]);
      h0[g] = fmaf(a.w, w0c[3], h0[g]);
      h1[g] = fmaf(a.x, w1c[0], h1[g]);
      h1[g] = fmaf(a.y, w1c[1], h1[g]);
      h1[g] = fmaf(a.z, w1c[2], h1[g]);
      h1[g] = fmaf(a.w, w1c[3], h1[g]);
    }
#pragma unroll
    for (int u = 0; u < 4; ++u) { w0c[u] = w0n[u]; w1c[u] = w1n[u]; }
  }

  const float wc2a = Wc2[c0], wc2b = Wc2[c1];
  const float bout = bc2[0];
#pragma unroll
  for (int g = 0; g < 8; ++g) {
    float p = fmaxf(h0[g], 0.f) * wc2a + fmaxf(h1[g], 0.f) * wc2b;
#pragma unroll
    for (int off = 32; off; off >>= 1) p += __shfl_xor(p, off);
    if (lane == 0) {
      int n = n0 + gbase + g;
      if (n < Nn) out[n] = p + bout;
    }
  }
}

// ---------------------------------------------------------------------------
extern "C" void kernel_launch(void* const* d_in, const int* in_sizes, int n_in,
                              void* d_out, int out_size, void* d_ws, size_t ws_size,
                              hipStream_t stream) {
  const int Nn = out_size;          // 40000
  const int E  = in_sizes[1] / 2;   // 600000

  // workspace carve (reused across categories except agg[])
  char* base = (char*)d_ws;
  size_t off = 0;
  auto carve = [&](size_t bytes) -> void* {
    off = (off + 255) & ~(size_t)255;
    void* p = base + off;
    off += bytes;
    return p;
  };
  float* xw = (float*)carve((size_t)Nn * 128 * 4);
  float* agg[3];
  for (int i = 0; i < 3; ++i) agg[i] = (float*)carve((size_t)Nn * 128 * 4);
  float* a_src = (float*)carve((size_t)Nn * 2 * 4);
  float* a_dst = (float*)carve((size_t)Nn * 2 * 4);
  int* deg  = (int*)carve((size_t)Nn * 4);
  int* offs = (int*)carve((size_t)(Nn + 1) * 4);
  int* bsum = (int*)carve(64 * 4);
  int* boff = (int*)carve(64 * 4);
  int* fill = (int*)carve((size_t)Nn * 4);
  int* adj  = (int*)carve((size_t)(E + Nn) * 4);
  float2* el = (float2*)carve((size_t)(E + Nn) * 8);
  (void)ws_size; (void)n_in;

  const int nscan = (Nn + 1023) / 1024;

  for (int cat = 0; cat < 3; ++cat) {
    const float* x   = (const float*)d_in[6 * cat + 0];
    const int*   ei  = (const int*)  d_in[6 * cat + 1];
    const float* W   = (const float*)d_in[6 * cat + 2];
    const float* ats = (const float*)d_in[6 * cat + 3];
    const float* atd = (const float*)d_in[6 * cat + 4];
    const int K = in_sizes[6 * cat] / Nn;

    gemm_xw<<<(Nn + TM - 1) / TM, 256, 0, stream>>>(x, W, xw, Nn, K);
    att_dots<<<((size_t)Nn * 64 + 255) / 256, 256, 0, stream>>>(xw, ats, atd, a_src, a_dst, Nn);
    zero2<<<(Nn + 255) / 256, 256, 0, stream>>>(deg, fill, Nn);
    hist_deg<<<(E + 255) / 256, 256, 0, stream>>>(ei + E, E, deg);
    scan_reduce<<<nscan, 1024, 0, stream>>>(deg, Nn, bsum);
    scan_tops<<<1, 64, 0, stream>>>(bsum, nscan, boff);
    scan_final<<<nscan, 1024, 0, stream>>>(deg, Nn, boff, offs);
    fill_adj<<<(E + Nn + 255) / 256, 256, 0, stream>>>(ei, ei + E, E, Nn, offs, a_src, a_dst, fill, adj, el);
    aggregate<<<((size_t)Nn * 64 + 255) / 256, 256, 0, stream>>>(xw, offs, adj, el, agg[cat], Nn);
  }

  final_mlp<<<(Nn + GNODES - 1) / GNODES, 256, 0, stream>>>(
      agg[0], agg[1], agg[2],
      (const float*)d_in[5], (const float*)d_in[11], (const float*)d_in[17],
      (const float*)d_in[18], (const float*)d_in[19],
      (const float*)d_in[20], (const float*)d_in[21],
      (float*)d_out, Nn);
}

// Round 4
// 625.824 us; speedup vs baseline: 1.4831x; 1.0667x over previous
//
#include <hip/hip_runtime.h>
#include <cstdint>
#include <cstddef>

// ---------------------------------------------------------------------------
// FCAGAT: 3x GATConv (H=2, C=64) + ELU + concat + MLP(384->128->1)
//   K1 gemm_xw     : xw = x @ W            [N,K]@[K,128] fp32 tiled GEMM
//   K2 att_dots    : a_src/a_dst[n,h] = <xw[n,h,:], att>   (wave per node)
//   K3 zero2+hist  : degree histogram over dst
//   K4 scan_*      : exclusive prefix sum -> CSR offsets
//   K5 fill_adj    : scatter src ids + PRE-COMPUTED logits (e0,e1) into CSR
//   K6 aggregate   : wave per dst: lane-parallel softmax stats (shfl butterfly)
//                    + chunked weighted gather (weights exp'd once per edge)
//   K7 final_mlp   : tiled GEMM [N,384]@[384,128] with fused elu-staging of A,
//                    LDS-shared Wc1 tiles, fused relu+Wc2 reduction epilogue.
// ---------------------------------------------------------------------------

__device__ __forceinline__ float lrelu02(float x) { return x > 0.f ? x : 0.2f * x; }
__device__ __forceinline__ float elu1(float x) { return x > 0.f ? x : (__expf(x) - 1.f); }

// ---------------- K1: XW = X[M,K] @ W[K,128] ----------------
#define TM 64
#define TN 128
#define TKK 32
__global__ __launch_bounds__(256) void gemm_xw(
    const float* __restrict__ X, const float* __restrict__ W,
    float* __restrict__ XW, int M, int K) {
  __shared__ __align__(16) float xs[TKK][TM];   // transposed x tile
  __shared__ __align__(16) float ws[TKK][TN];
  const int tid = threadIdx.x;
  const int tx = tid & 15;        // col group -> cols tx*8..+7
  const int ty = tid >> 4;        // row group -> rows ty*4..+3
  const int row0 = blockIdx.x * TM;
  float acc[4][8];
#pragma unroll
  for (int r = 0; r < 4; ++r)
#pragma unroll
    for (int c = 0; c < 8; ++c) acc[r][c] = 0.f;

  const int lr = tid >> 2;        // 0..63 : x row within tile
  const int lk = (tid & 3) * 8;   // x k offset
  const int wr = tid >> 3;        // 0..31 : W k row
  const int wc = (tid & 7) * 16;  // W col offset

  for (int k0 = 0; k0 < K; k0 += TKK) {
    int xrow = row0 + lr; if (xrow >= M) xrow = M - 1;   // clamp (loads only)
    const float4* xp = (const float4*)(X + (size_t)xrow * K + k0 + lk);
    float4 xa = xp[0];
    float4 xb = xp[1];
    const float4* wp = (const float4*)(W + (size_t)(k0 + wr) * TN + wc);
    float4 w0 = wp[0], w1 = wp[1], w2 = wp[2], w3 = wp[3];
    __syncthreads();
    xs[lk + 0][lr] = xa.x; xs[lk + 1][lr] = xa.y; xs[lk + 2][lr] = xa.z; xs[lk + 3][lr] = xa.w;
    xs[lk + 4][lr] = xb.x; xs[lk + 5][lr] = xb.y; xs[lk + 6][lr] = xb.z; xs[lk + 7][lr] = xb.w;
    *(float4*)&ws[wr][wc + 0]  = w0;
    *(float4*)&ws[wr][wc + 4]  = w1;
    *(float4*)&ws[wr][wc + 8]  = w2;
    *(float4*)&ws[wr][wc + 12] = w3;
    __syncthreads();
#pragma unroll
    for (int k = 0; k < TKK; ++k) {
      float4 a = *(const float4*)&xs[k][ty * 4];
      float4 b0 = *(const float4*)&ws[k][tx * 8];
      float4 b1 = *(const float4*)&ws[k][tx * 8 + 4];
      float av[4] = {a.x, a.y, a.z, a.w};
      float bv[8] = {b0.x, b0.y, b0.z, b0.w, b1.x, b1.y, b1.z, b1.w};
#pragma unroll
      for (int r = 0; r < 4; ++r)
#pragma unroll
        for (int c = 0; c < 8; ++c)
          acc[r][c] = fmaf(av[r], bv[c], acc[r][c]);
    }
  }
#pragma unroll
  for (int r = 0; r < 4; ++r) {
    int row = row0 + ty * 4 + r;
    if (row < M) {
      float4 o0 = {acc[r][0], acc[r][1], acc[r][2], acc[r][3]};
      float4 o1 = {acc[r][4], acc[r][5], acc[r][6], acc[r][7]};
      float4* op = (float4*)(XW + (size_t)row * TN + tx * 8);
      op[0] = o0; op[1] = o1;
    }
  }
}

// ---------------- K2: attention dots, wave per node ----------------
__global__ __launch_bounds__(256) void att_dots(
    const float* __restrict__ xw, const float* __restrict__ att_s,
    const float* __restrict__ att_d, float* __restrict__ a_src,
    float* __restrict__ a_dst, int Nn) {
  int wave = (int)((blockIdx.x * (size_t)blockDim.x + threadIdx.x) >> 6);
  int lane = threadIdx.x & 63;
  if (wave >= Nn) return;
  float x0 = xw[(size_t)wave * 128 + lane];
  float x1 = xw[(size_t)wave * 128 + 64 + lane];
  float s0 = x0 * att_s[lane];
  float s1 = x1 * att_s[64 + lane];
  float d0 = x0 * att_d[lane];
  float d1 = x1 * att_d[64 + lane];
#pragma unroll
  for (int off = 32; off; off >>= 1) {
    s0 += __shfl_xor(s0, off);
    s1 += __shfl_xor(s1, off);
    d0 += __shfl_xor(d0, off);
    d1 += __shfl_xor(d1, off);
  }
  if (lane == 0) {
    a_src[wave * 2 + 0] = s0;
    a_src[wave * 2 + 1] = s1;
    a_dst[wave * 2 + 0] = d0;
    a_dst[wave * 2 + 1] = d1;
  }
}

// ---------------- K3: zero + degree histogram ----------------
__global__ void zero2(int* __restrict__ a, int* __restrict__ b, int Nn) {
  int i = blockIdx.x * blockDim.x + threadIdx.x;
  if (i < Nn) { a[i] = 0; b[i] = 0; }
}

__global__ void hist_deg(const int* __restrict__ dst, int E, int* __restrict__ deg) {
  int i = blockIdx.x * blockDim.x + threadIdx.x;
  if (i < E) atomicAdd(&deg[dst[i]], 1);
}

// ---------------- K4: 3-phase exclusive scan of (deg[i]+1) ----------------
__global__ __launch_bounds__(1024) void scan_reduce(
    const int* __restrict__ deg, int Nn, int* __restrict__ bsum) {
  __shared__ int wsum[16];
  int tid = threadIdx.x;
  int gi = blockIdx.x * 1024 + tid;
  int x = (gi < Nn) ? (deg[gi] + 1) : 0;
#pragma unroll
  for (int off = 32; off; off >>= 1) x += __shfl_xor(x, off);
  int lane = tid & 63, wid = tid >> 6;
  if (lane == 0) wsum[wid] = x;
  __syncthreads();
  if (tid == 0) {
    int s = 0;
#pragma unroll
    for (int i = 0; i < 16; ++i) s += wsum[i];
    bsum[blockIdx.x] = s;
  }
}

__global__ void scan_tops(const int* __restrict__ bsum, int nb, int* __restrict__ boff) {
  int lane = threadIdx.x;   // 64 threads
  int v = (lane < nb) ? bsum[lane] : 0;
  int orig = v;
#pragma unroll
  for (int off = 1; off < 64; off <<= 1) {
    int t = __shfl_up(v, off);
    if (lane >= off) v += t;
  }
  if (lane < nb) boff[lane] = v - orig;   // exclusive
}

__global__ __launch_bounds__(1024) void scan_final(
    const int* __restrict__ deg, int Nn, const int* __restrict__ boff,
    int* __restrict__ offs) {
  __shared__ int wsum[16];
  int tid = threadIdx.x;
  int gi = blockIdx.x * 1024 + tid;
  int x = (gi < Nn) ? (deg[gi] + 1) : 0;
  int lane = tid & 63, wid = tid >> 6;
  int v = x;
#pragma unroll
  for (int off = 1; off < 64; off <<= 1) {
    int t = __shfl_up(v, off);
    if (lane >= off) v += t;
  }
  if (lane == 63) wsum[wid] = v;
  __syncthreads();
  if (wid == 0) {
    int wv = (lane < 16) ? wsum[lane] : 0;
#pragma unroll
    for (int off = 1; off < 16; off <<= 1) {
      int t = __shfl_up(wv, off);
      if (lane >= off) wv += t;
    }
    if (lane < 16) wsum[lane] = wv;   // inclusive wave sums
  }
  __syncthreads();
  int pre = (wid > 0 ? wsum[wid - 1] : 0) + boff[blockIdx.x];
  if (gi < Nn) offs[gi + 1] = pre + v;
  if (gi == 0) offs[0] = 0;
}

// ---------------- K5: fill CSR adjacency + per-edge logits ----------------
__global__ void fill_adj(const int* __restrict__ src, const int* __restrict__ dst,
                         int E, int Nn, const int* __restrict__ offs,
                         const float* __restrict__ a_src, const float* __restrict__ a_dst,
                         int* __restrict__ fill, int* __restrict__ adj,
                         float2* __restrict__ el) {
  int i = blockIdx.x * blockDim.x + threadIdx.x;
  int tot = E + Nn;
  if (i >= tot) return;
  int s, d;
  if (i < E) { s = src[i]; d = dst[i]; }
  else { s = i - E; d = i - E; }
  int p = offs[d] + atomicAdd(&fill[d], 1);
  adj[p] = s;
  float e0 = lrelu02(a_src[s * 2 + 0] + a_dst[d * 2 + 0]);
  float e1 = lrelu02(a_src[s * 2 + 1] + a_dst[d * 2 + 1]);
  el[p] = make_float2(e0, e1);
}

// ---------------- K6: lane-parallel segment softmax + chunked gather ----------------
__global__ __launch_bounds__(256) void aggregate(
    const float* __restrict__ xw, const int* __restrict__ offs,
    const int* __restrict__ adj, const float2* __restrict__ el,
    float* __restrict__ agg, int Nn) {
  const int wave = (int)((blockIdx.x * (size_t)blockDim.x + threadIdx.x) >> 6);
  const int lane = threadIdx.x & 63;
  if (wave >= Nn) return;
  const int base = offs[wave], end = offs[wave + 1];

  // phase 1: lane-strided online softmax stats, then butterfly merge
  float m0 = -1e30f, s0 = 0.f, m1 = -1e30f, s1 = 0.f;
  for (int j = base + lane; j < end; j += 64) {
    float2 e = el[j];
    float nm0 = fmaxf(m0, e.x);
    s0 = s0 * __expf(m0 - nm0) + __expf(e.x - nm0); m0 = nm0;
    float nm1 = fmaxf(m1, e.y);
    s1 = s1 * __expf(m1 - nm1) + __expf(e.y - nm1); m1 = nm1;
  }
#pragma unroll
  for (int off = 32; off; off >>= 1) {
    float om0 = __shfl_xor(m0, off), os0 = __shfl_xor(s0, off);
    float nm0 = fmaxf(m0, om0);
    s0 = s0 * __expf(m0 - nm0) + os0 * __expf(om0 - nm0); m0 = nm0;
    float om1 = __shfl_xor(m1, off), os1 = __shfl_xor(s1, off);
    float nm1 = fmaxf(m1, om1);
    s1 = s1 * __expf(m1 - nm1) + os1 * __expf(om1 - nm1); m1 = nm1;
  }
  const float inv0 = 1.f / s0, inv1 = 1.f / s1;

  // phase 2: chunks of 64 edges; weight exp'd once per edge (by its lane),
  // then broadcast via shfl; gathers unrolled x4 for memory-level parallelism
  float acc0 = 0.f, acc1 = 0.f;
  for (int cb = base; cb < end; cb += 64) {
    const int cnt = min(64, end - cb);
    int srcv = 0; float w0v = 0.f, w1v = 0.f;
    if (lane < cnt) {
      srcv = adj[cb + lane];
      float2 e = el[cb + lane];
      w0v = __expf(e.x - m0) * inv0;
      w1v = __expf(e.y - m1) * inv1;
    }
    int k = 0;
    for (; k + 4 <= cnt; k += 4) {
      int sa = __shfl(srcv, k),     sb = __shfl(srcv, k + 1);
      int sc = __shfl(srcv, k + 2), sd = __shfl(srcv, k + 3);
      float wa0 = __shfl(w0v, k),     wb0 = __shfl(w0v, k + 1);
      float wc0 = __shfl(w0v, k + 2), wd0 = __shfl(w0v, k + 3);
      float wa1 = __shfl(w1v, k),     wb1 = __shfl(w1v, k + 1);
      float wc1 = __shfl(w1v, k + 2), wd1 = __shfl(w1v, k + 3);
      const float* pa = xw + (size_t)sa * 128 + lane;
      const float* pb = xw + (size_t)sb * 128 + lane;
      const float* pc = xw + (size_t)sc * 128 + lane;
      const float* pd = xw + (size_t)sd * 128 + lane;
      float xa0 = pa[0], xa1 = pa[64];
      float xb0 = pb[0], xb1 = pb[64];
      float xc0 = pc[0], xc1 = pc[64];
      float xd0 = pd[0], xd1 = pd[64];
      acc0 = fmaf(wa0, xa0, acc0); acc1 = fmaf(wa1, xa1, acc1);
      acc0 = fmaf(wb0, xb0, acc0); acc1 = fmaf(wb1, xb1, acc1);
      acc0 = fmaf(wc0, xc0, acc0); acc1 = fmaf(wc1, xc1, acc1);
      acc0 = fmaf(wd0, xd0, acc0); acc1 = fmaf(wd1, xd1, acc1);
    }
    for (; k < cnt; ++k) {
      int s = __shfl(srcv, k);
      float w0 = __shfl(w0v, k);
      float w1 = __shfl(w1v, k);
      const float* p = xw + (size_t)s * 128 + lane;
      acc0 = fmaf(w0, p[0], acc0);
      acc1 = fmaf(w1, p[64], acc1);
    }
  }
  agg[(size_t)wave * 128 + lane] = acc0;
  agg[(size_t)wave * 128 + 64 + lane] = acc1;
}

// ---------------- K7: final MLP as tiled GEMM with fused staging/epilogue ----
// C[64-row tile] = elu(agg+bias)[64,384] @ Wc1[384,128]; then relu(+bc1),
// dot Wc2, cross-thread reduce -> out. Wc1 tiles staged once per block in LDS.
__global__ __launch_bounds__(256) void final_mlp(
    const float* __restrict__ agg0, const float* __restrict__ agg1,
    const float* __restrict__ agg2, const float* __restrict__ bias0,
    const float* __restrict__ bias1, const float* __restrict__ bias2,
    const float* __restrict__ Wc1, const float* __restrict__ bc1,
    const float* __restrict__ Wc2, const float* __restrict__ bc2,
    float* __restrict__ out, int Nn) {
  __shared__ __align__(16) float hs[TKK][TM];    // 8 KB  transposed H tile
  __shared__ __align__(16) float wsW[TKK][TN];   // 16 KB Wc1 tile
  __shared__ float red[TM][17];                  // 4.25 KB epilogue reduce
  const int tid = threadIdx.x;
  const int tx = tid & 15;        // col group -> cols tx*8..+7
  const int ty = tid >> 4;        // row group -> rows ty*4..+3
  const int row0 = blockIdx.x * TM;
  float acc[4][8];
#pragma unroll
  for (int r = 0; r < 4; ++r)
#pragma unroll
    for (int c = 0; c < 8; ++c) acc[r][c] = 0.f;

  const int lr = tid >> 2;        // 0..63 : H row within tile
  const int lk = (tid & 3) * 8;   // H k offset (0,8,16,24)
  const int wr = tid >> 3;        // 0..31 : Wc1 k row
  const int wc = (tid & 7) * 16;  // Wc1 col offset

  for (int k0 = 0; k0 < 384; k0 += TKK) {
    int row = row0 + lr; if (row >= Nn) row = Nn - 1;
    const int kg = k0 + lk;                  // 8-aligned: single source segment
    const int sel = kg >> 7, q = kg & 127;
    const float* aggp = (sel == 0) ? agg0 : (sel == 1) ? agg1 : agg2;
    const float* bp   = (sel == 0) ? bias0 : (sel == 1) ? bias1 : bias2;
    float4 xa = *(const float4*)(aggp + (size_t)row * 128 + q);
    float4 xb = *(const float4*)(aggp + (size_t)row * 128 + q + 4);
    float4 ba = *(const float4*)(bp + q);
    float4 bb = *(const float4*)(bp + q + 4);
    xa.x = elu1(xa.x + ba.x); xa.y = elu1(xa.y + ba.y);
    xa.z = elu1(xa.z + ba.z); xa.w = elu1(xa.w + ba.w);
    xb.x = elu1(xb.x + bb.x); xb.y = elu1(xb.y + bb.y);
    xb.z = elu1(xb.z + bb.z); xb.w = elu1(xb.w + bb.w);
    const float4* wp = (const float4*)(Wc1 + (size_t)(k0 + wr) * TN + wc);
    float4 w0 = wp[0], w1 = wp[1], w2 = wp[2], w3 = wp[3];
    __syncthreads();
    hs[lk + 0][lr] = xa.x; hs[lk + 1][lr] = xa.y; hs[lk + 2][lr] = xa.z; hs[lk + 3][lr] = xa.w;
    hs[lk + 4][lr] = xb.x; hs[lk + 5][lr] = xb.y; hs[lk + 6][lr] = xb.z; hs[lk + 7][lr] = xb.w;
    *(float4*)&wsW[wr][wc + 0]  = w0;
    *(float4*)&wsW[wr][wc + 4]  = w1;
    *(float4*)&wsW[wr][wc + 8]  = w2;
    *(float4*)&wsW[wr][wc + 12] = w3;
    __syncthreads();
#pragma unroll
    for (int k = 0; k < TKK; ++k) {
      float4 a = *(const float4*)&hs[k][ty * 4];
      float4 b0 = *(const float4*)&wsW[k][tx * 8];
      float4 b1 = *(const float4*)&wsW[k][tx * 8 + 4];
      float av[4] = {a.x, a.y, a.z, a.w};
      float bv[8] = {b0.x, b0.y, b0.z, b0.w, b1.x, b1.y, b1.z, b1.w};
#pragma unroll
      for (int r = 0; r < 4; ++r)
#pragma unroll
        for (int c = 0; c < 8; ++c)
          acc[r][c] = fmaf(av[r], bv[c], acc[r][c]);
    }
  }

  // epilogue: hid = relu(acc + bc1[col]); partial = <hid, Wc2[col]>
  float bcv[8], w2v[8];
#pragma unroll
  for (int c = 0; c < 8; ++c) {
    bcv[c] = bc1[tx * 8 + c];
    w2v[c] = Wc2[tx * 8 + c];
  }
  float part[4];
#pragma unroll
  for (int r = 0; r < 4; ++r) {
    float p = 0.f;
#pragma unroll
    for (int c = 0; c < 8; ++c)
      p = fmaf(fmaxf(acc[r][c] + bcv[c], 0.f), w2v[c], p);
    part[r] = p;
  }
#pragma unroll
  for (int r = 0; r < 4; ++r) red[ty * 4 + r][tx] = part[r];
  __syncthreads();
  if (tid < TM) {
    float s = 0.f;
#pragma unroll
    for (int i = 0; i < 16; ++i) s += red[tid][i];
    int n = row0 + tid;
    if (n < Nn) out[n] = s + bc2[0];
  }
}

// ---------------------------------------------------------------------------
extern "C" void kernel_launch(void* const* d_in, const int* in_sizes, int n_in,
                              void* d_out, int out_size, void* d_ws, size_t ws_size,
                              hipStream_t stream) {
  const int Nn = out_size;          // 40000
  const int E  = in_sizes[1] / 2;   // 600000

  // workspace carve (reused across categories except agg[])
  char* base = (char*)d_ws;
  size_t off = 0;
  auto carve = [&](size_t bytes) -> void* {
    off = (off + 255) & ~(size_t)255;
    void* p = base + off;
    off += bytes;
    return p;
  };
  float* xw = (float*)carve((size_t)Nn * 128 * 4);
  float* agg[3];
  for (int i = 0; i < 3; ++i) agg[i] = (float*)carve((size_t)Nn * 128 * 4);
  float* a_src = (float*)carve((size_t)Nn * 2 * 4);
  float* a_dst = (float*)carve((size_t)Nn * 2 * 4);
  int* deg  = (int*)carve((size_t)Nn * 4);
  int* offs = (int*)carve((size_t)(Nn + 1) * 4);
  int* bsum = (int*)carve(64 * 4);
  int* boff = (int*)carve(64 * 4);
  int* fill = (int*)carve((size_t)Nn * 4);
  int* adj  = (int*)carve((size_t)(E + Nn) * 4);
  float2* el = (float2*)carve((size_t)(E + Nn) * 8);
  (void)ws_size; (void)n_in;

  const int nscan = (Nn + 1023) / 1024;

  for (int cat = 0; cat < 3; ++cat) {
    const float* x   = (const float*)d_in[6 * cat + 0];
    const int*   ei  = (const int*)  d_in[6 * cat + 1];
    const float* W   = (const float*)d_in[6 * cat + 2];
    const float* ats = (const float*)d_in[6 * cat + 3];
    const float* atd = (const float*)d_in[6 * cat + 4];
    const int K = in_sizes[6 * cat] / Nn;

    gemm_xw<<<(Nn + TM - 1) / TM, 256, 0, stream>>>(x, W, xw, Nn, K);
    att_dots<<<((size_t)Nn * 64 + 255) / 256, 256, 0, stream>>>(xw, ats, atd, a_src, a_dst, Nn);
    zero2<<<(Nn + 255) / 256, 256, 0, stream>>>(deg, fill, Nn);
    hist_deg<<<(E + 255) / 256, 256, 0, stream>>>(ei + E, E, deg);
    scan_reduce<<<nscan, 1024, 0, stream>>>(deg, Nn, bsum);
    scan_tops<<<1, 64, 0, stream>>>(bsum, nscan, boff);
    scan_final<<<nscan, 1024, 0, stream>>>(deg, Nn, boff, offs);
    fill_adj<<<(E + Nn + 255) / 256, 256, 0, stream>>>(ei, ei + E, E, Nn, offs, a_src, a_dst, fill, adj, el);
    aggregate<<<((size_t)Nn * 64 + 255) / 256, 256, 0, stream>>>(xw, offs, adj, el, agg[cat], Nn);
  }

  final_mlp<<<(Nn + TM - 1) / TM, 256, 0, stream>>>(
      agg[0], agg[1], agg[2],
      (const float*)d_in[5], (const float*)d_in[11], (const float*)d_in[17],
      (const float*)d_in[18], (const float*)d_in[19],
      (const float*)d_in[20], (const float*)d_in[21],
      (float*)d_out, Nn);
}

// Round 5
// 565.445 us; speedup vs baseline: 1.6415x; 1.1068x over previous
//
#include <hip/hip_runtime.h>
#include <cstdint>
#include <cstddef>

// ---------------------------------------------------------------------------
// FCAGAT: 3x GATConv (H=2, C=64) + ELU + concat + MLP(384->128->1)
// Batched CSR build over all 3 category graphs (flattened 3N nodes), then
// per-cat: gemm(+fused att dots) -> aggregate; then fused MLP head.
//   K1 zero3       : deg3/fill3 = 0                      [3N]
//   K2 hist_b      : batched degree histogram            [3E]
//   K3-5 scan_*    : exclusive prefix sum of deg+1 -> offs3 [3N+1]
//   K6 fill_b      : batched CSR adjacency (edges + self loops)
//   K7 gemm_att    : xw = x@W tiled GEMM, swizzled LDS (conflict-free),
//                    epilogue computes a_src/a_dst via 8-lane shfl tree
//   K8 aggregate   : wave/node: lane-parallel online softmax (logits kept in
//                    regs for deg<=64) + shfl-broadcast weighted gather
//   K9 final_mlp   : tiled GEMM elu(agg+b)[N,384]@Wc1, swizzled LDS, fused
//                    relu+Wc2 reduction epilogue
// LDS swizzles (measured 1.2e7 conflict cycles in R3 -> fix):
//   A tile (transposed) : col' = row ^ (((k>>3)&1)*16)   (writes 2-way=free)
//   B tile (float4 blk) : b'   = b ^ (2*(b>>3))          (reads spread 8 groups)
// ---------------------------------------------------------------------------

__device__ __forceinline__ float lrelu02(float x) { return x > 0.f ? x : 0.2f * x; }
__device__ __forceinline__ float elu1(float x) { return x > 0.f ? x : (__expf(x) - 1.f); }

#define TM 64
#define TN 128
#define TKK 32

// ---------------- K7: XW = X[M,K] @ W[K,128] + fused attention dots ----------
__global__ __launch_bounds__(256) void gemm_att(
    const float* __restrict__ X, const float* __restrict__ W,
    const float* __restrict__ att_s, const float* __restrict__ att_d,
    float* __restrict__ XW, float* __restrict__ a_src, float* __restrict__ a_dst,
    int M, int K) {
  __shared__ __align__(16) float xs[TKK][TM];     // 8 KB, swizzled transposed A
  __shared__ __align__(16) float4 wsB[TKK][TN/4]; // 16 KB, swizzled B
  const int tid = threadIdx.x;
  const int tx = tid & 15;        // col group -> cols tx*8..+7
  const int ty = tid >> 4;        // row group -> rows ty*4..+3
  const int row0 = blockIdx.x * TM;
  float acc[4][8];
#pragma unroll
  for (int r = 0; r < 4; ++r)
#pragma unroll
    for (int c = 0; c < 8; ++c) acc[r][c] = 0.f;

  const int lr = tid >> 2;        // 0..63 : A row within tile
  const int lk = (tid & 3) * 8;   // A k offset {0,8,16,24}
  const int wr = tid >> 3;        // 0..31 : B k row
  const int bb = (tid & 7) * 4;   // B float4-block base (0..28)
  const int xcol = lr ^ (((lk >> 3) & 1) * 16);   // A swizzle (k-block parity)
  const int p0 = (tx * 2) ^ (2 * ((tx * 2) >> 3));
  const int p1 = (tx * 2 + 1) ^ (2 * ((tx * 2 + 1) >> 3));

  for (int k0 = 0; k0 < K; k0 += TKK) {
    int xrow = row0 + lr; if (xrow >= M) xrow = M - 1;   // clamp (loads only)
    const float4* xp = (const float4*)(X + (size_t)xrow * K + k0 + lk);
    float4 xa = xp[0];
    float4 xb = xp[1];
    const float4* wp = (const float4*)(W + (size_t)(k0 + wr) * TN + bb * 4);
    float4 w0 = wp[0], w1 = wp[1], w2 = wp[2], w3 = wp[3];
    __syncthreads();
    xs[lk + 0][xcol] = xa.x; xs[lk + 1][xcol] = xa.y;
    xs[lk + 2][xcol] = xa.z; xs[lk + 3][xcol] = xa.w;
    xs[lk + 4][xcol] = xb.x; xs[lk + 5][xcol] = xb.y;
    xs[lk + 6][xcol] = xb.z; xs[lk + 7][xcol] = xb.w;
    {
      int b0i = bb + 0; wsB[wr][b0i ^ (2 * (b0i >> 3))] = w0;
      int b1i = bb + 1; wsB[wr][b1i ^ (2 * (b1i >> 3))] = w1;
      int b2i = bb + 2; wsB[wr][b2i ^ (2 * (b2i >> 3))] = w2;
      int b3i = bb + 3; wsB[wr][b3i ^ (2 * (b3i >> 3))] = w3;
    }
    __syncthreads();
#pragma unroll
    for (int k = 0; k < TKK; ++k) {
      const int acol = (ty * 4) ^ (((k >> 3) & 1) * 16);
      float4 a = *(const float4*)&xs[k][acol];
      float4 b0 = wsB[k][p0];
      float4 b1 = wsB[k][p1];
      float av[4] = {a.x, a.y, a.z, a.w};
      float bv[8] = {b0.x, b0.y, b0.z, b0.w, b1.x, b1.y, b1.z, b1.w};
#pragma unroll
      for (int r = 0; r < 4; ++r)
#pragma unroll
        for (int c = 0; c < 8; ++c)
          acc[r][c] = fmaf(av[r], bv[c], acc[r][c]);
    }
  }
  // store xw
#pragma unroll
  for (int r = 0; r < 4; ++r) {
    int row = row0 + ty * 4 + r;
    if (row < M) {
      float4 o0 = {acc[r][0], acc[r][1], acc[r][2], acc[r][3]};
      float4 o1 = {acc[r][4], acc[r][5], acc[r][6], acc[r][7]};
      float4* op = (float4*)(XW + (size_t)row * TN + tx * 8);
      op[0] = o0; op[1] = o1;
    }
  }
  // fused attention dots: this thread's 8 cols all belong to head tx>>3
  float ps[4] = {0.f, 0.f, 0.f, 0.f}, pd[4] = {0.f, 0.f, 0.f, 0.f};
#pragma unroll
  for (int c = 0; c < 8; ++c) {
    float as = att_s[tx * 8 + c], ad = att_d[tx * 8 + c];
#pragma unroll
    for (int r = 0; r < 4; ++r) {
      ps[r] = fmaf(acc[r][c], as, ps[r]);
      pd[r] = fmaf(acc[r][c], ad, pd[r]);
    }
  }
#pragma unroll
  for (int off = 1; off < 8; off <<= 1) {
#pragma unroll
    for (int r = 0; r < 4; ++r) {
      ps[r] += __shfl_xor(ps[r], off);
      pd[r] += __shfl_xor(pd[r], off);
    }
  }
  if ((tx & 7) == 0) {
    int head = tx >> 3;
#pragma unroll
    for (int r = 0; r < 4; ++r) {
      int row = row0 + ty * 4 + r;
      if (row < M) {
        a_src[row * 2 + head] = ps[r];
        a_dst[row * 2 + head] = pd[r];
      }
    }
  }
}

// ---------------- K1: zero ----------------
__global__ void zero3(int* __restrict__ a, int* __restrict__ b, int n) {
  int i = blockIdx.x * blockDim.x + threadIdx.x;
  if (i < n) { a[i] = 0; b[i] = 0; }
}

// ---------------- K2: batched degree histogram ----------------
__global__ void hist_b(const int* __restrict__ ei0, const int* __restrict__ ei1,
                       const int* __restrict__ ei2, int E0, int E1, int E2,
                       int Nn, int* __restrict__ deg3) {
  int i = blockIdx.x * blockDim.x + threadIdx.x;
  int c1 = E0, c2 = E0 + E1, tot = c2 + E2;
  if (i >= tot) return;
  int d, gb;
  if (i < c1)      { d = ei0[E0 + i];        gb = 0; }
  else if (i < c2) { d = ei1[E1 + (i - c1)]; gb = Nn; }
  else             { d = ei2[E2 + (i - c2)]; gb = 2 * Nn; }
  atomicAdd(&deg3[gb + d], 1);
}

// ---------------- K3-5: 3-phase exclusive scan of (deg[i]+1) ----------------
__global__ __launch_bounds__(1024) void scan_reduce(
    const int* __restrict__ deg, int Nt, int* __restrict__ bsum) {
  __shared__ int wsum[16];
  int tid = threadIdx.x;
  int gi = blockIdx.x * 1024 + tid;
  int x = (gi < Nt) ? (deg[gi] + 1) : 0;
#pragma unroll
  for (int off = 32; off; off >>= 1) x += __shfl_xor(x, off);
  int lane = tid & 63, wid = tid >> 6;
  if (lane == 0) wsum[wid] = x;
  __syncthreads();
  if (tid == 0) {
    int s = 0;
#pragma unroll
    for (int i = 0; i < 16; ++i) s += wsum[i];
    bsum[blockIdx.x] = s;
  }
}

__global__ __launch_bounds__(128) void scan_tops2(
    const int* __restrict__ bsum, int nb, int* __restrict__ boff) {
  __shared__ int tmp[128];
  int tid = threadIdx.x;
  int v = (tid < nb) ? bsum[tid] : 0;
  int inc = v;
  tmp[tid] = v;
  __syncthreads();
  for (int off = 1; off < 128; off <<= 1) {
    int t = (tid >= off) ? tmp[tid - off] : 0;
    __syncthreads();
    tmp[tid] += t;
    __syncthreads();
  }
  if (tid < nb) boff[tid] = tmp[tid] - inc;
}

__global__ __launch_bounds__(1024) void scan_final(
    const int* __restrict__ deg, int Nt, const int* __restrict__ boff,
    int* __restrict__ offs) {
  __shared__ int wsum[16];
  int tid = threadIdx.x;
  int gi = blockIdx.x * 1024 + tid;
  int x = (gi < Nt) ? (deg[gi] + 1) : 0;
  int lane = tid & 63, wid = tid >> 6;
  int v = x;
#pragma unroll
  for (int off = 1; off < 64; off <<= 1) {
    int t = __shfl_up(v, off);
    if (lane >= off) v += t;
  }
  if (lane == 63) wsum[wid] = v;
  __syncthreads();
  if (wid == 0) {
    int wv = (lane < 16) ? wsum[lane] : 0;
#pragma unroll
    for (int off = 1; off < 16; off <<= 1) {
      int t = __shfl_up(wv, off);
      if (lane >= off) wv += t;
    }
    if (lane < 16) wsum[lane] = wv;   // inclusive wave sums
  }
  __syncthreads();
  int pre = (wid > 0 ? wsum[wid - 1] : 0) + boff[blockIdx.x];
  if (gi < Nt) offs[gi + 1] = pre + v;
  if (gi == 0) offs[0] = 0;
}

// ---------------- K6: batched CSR adjacency fill (edges + self loops) --------
__global__ void fill_b(const int* __restrict__ ei0, const int* __restrict__ ei1,
                       const int* __restrict__ ei2, int E0, int E1, int E2,
                       int Nn, const int* __restrict__ offs3,
                       int* __restrict__ fill3, int* __restrict__ adj) {
  int i = blockIdx.x * blockDim.x + threadIdx.x;
  int c1 = E0, c2 = E0 + E1, totE = c2 + E2, tot = totE + 3 * Nn;
  if (i >= tot) return;
  int s, d, cat;
  if (i < totE) {
    if (i < c1)      { s = ei0[i];            d = ei0[E0 + i];        cat = 0; }
    else if (i < c2) { int t = i - c1; s = ei1[t]; d = ei1[E1 + t];   cat = 1; }
    else             { int t = i - c2; s = ei2[t]; d = ei2[E2 + t];   cat = 2; }
  } else {
    int j = i - totE;
    cat = (j < Nn) ? 0 : (j < 2 * Nn) ? 1 : 2;
    int n = j - cat * Nn;
    s = n; d = n;
  }
  int g = cat * Nn + d;
  int p = offs3[g] + atomicAdd(&fill3[g], 1);
  adj[p] = s;   // local src id (per-cat xw buffer)
}

// ---------------- K8: lane-parallel segment softmax + gather ----------------
__global__ __launch_bounds__(256) void aggregate(
    const float* __restrict__ xw, const float* __restrict__ a_src,
    const float* __restrict__ a_dst, const int* __restrict__ offs,
    const int* __restrict__ adj, float* __restrict__ agg, int Nn) {
  const int node = (int)((blockIdx.x * (size_t)blockDim.x + threadIdx.x) >> 6);
  const int lane = threadIdx.x & 63;
  if (node >= Nn) return;
  const int base = offs[node], end = offs[node + 1];
  const float2 ad = ((const float2*)a_dst)[node];

  // phase 1: lane-strided online softmax stats; keep first chunk in regs
  float m0 = -1e30f, s0 = 0.f, m1 = -1e30f, s1 = 0.f;
  int sv0 = 0; float ex0 = -1e30f, ey0 = -1e30f;
  for (int cb = base; cb < end; cb += 64) {
    int j = cb + lane;
    int sv = 0; float ex = -1e30f, ey = -1e30f;
    if (j < end) {
      sv = adj[j];
      float2 as = ((const float2*)a_src)[sv];
      ex = lrelu02(as.x + ad.x);
      ey = lrelu02(as.y + ad.y);
      float nm0 = fmaxf(m0, ex);
      s0 = s0 * __expf(m0 - nm0) + __expf(ex - nm0); m0 = nm0;
      float nm1 = fmaxf(m1, ey);
      s1 = s1 * __expf(m1 - nm1) + __expf(ey - nm1); m1 = nm1;
    }
    if (cb == base) { sv0 = sv; ex0 = ex; ey0 = ey; }
  }
#pragma unroll
  for (int off = 32; off; off >>= 1) {
    float om0 = __shfl_xor(m0, off), os0 = __shfl_xor(s0, off);
    float nm0 = fmaxf(m0, om0);
    s0 = s0 * __expf(m0 - nm0) + os0 * __expf(om0 - nm0); m0 = nm0;
    float om1 = __shfl_xor(m1, off), os1 = __shfl_xor(s1, off);
    float nm1 = fmaxf(m1, om1);
    s1 = s1 * __expf(m1 - nm1) + os1 * __expf(om1 - nm1); m1 = nm1;
  }
  const float inv0 = 1.f / s0, inv1 = 1.f / s1;

  // phase 2: weight once per edge (its lane), shfl-broadcast, gather x4
  float acc0 = 0.f, acc1 = 0.f;
  for (int cb = base; cb < end; cb += 64) {
    const int cnt = min(64, end - cb);
    int srcv; float w0v, w1v;
    if (cb == base) {
      srcv = sv0;
      w0v = __expf(ex0 - m0) * inv0;   // inactive lanes: exp(-inf)=0
      w1v = __expf(ey0 - m1) * inv1;
    } else {
      srcv = 0; float ex = -1e30f, ey = -1e30f;
      if (lane < cnt) {
        srcv = adj[cb + lane];
        float2 as = ((const float2*)a_src)[srcv];
        ex = lrelu02(as.x + ad.x);
        ey = lrelu02(as.y + ad.y);
      }
      w0v = __expf(ex - m0) * inv0;
      w1v = __expf(ey - m1) * inv1;
    }
    int k = 0;
    for (; k + 4 <= cnt; k += 4) {
      int sa = __shfl(srcv, k),     sb = __shfl(srcv, k + 1);
      int sc = __shfl(srcv, k + 2), sd = __shfl(srcv, k + 3);
      float wa0 = __shfl(w0v, k),     wb0 = __shfl(w0v, k + 1);
      float wc0 = __shfl(w0v, k + 2), wd0 = __shfl(w0v, k + 3);
      float wa1 = __shfl(w1v, k),     wb1 = __shfl(w1v, k + 1);
      float wc1 = __shfl(w1v, k + 2), wd1 = __shfl(w1v, k + 3);
      const float* pa = xw + (size_t)sa * 128 + lane;
      const float* pb = xw + (size_t)sb * 128 + lane;
      const float* pc = xw + (size_t)sc * 128 + lane;
      const float* pd = xw + (size_t)sd * 128 + lane;
      float xa0 = pa[0], xa1 = pa[64];
      float xb0 = pb[0], xb1 = pb[64];
      float xc0 = pc[0], xc1 = pc[64];
      float xd0 = pd[0], xd1 = pd[64];
      acc0 = fmaf(wa0, xa0, acc0); acc1 = fmaf(wa1, xa1, acc1);
      acc0 = fmaf(wb0, xb0, acc0); acc1 = fmaf(wb1, xb1, acc1);
      acc0 = fmaf(wc0, xc0, acc0); acc1 = fmaf(wc1, xc1, acc1);
      acc0 = fmaf(wd0, xd0, acc0); acc1 = fmaf(wd1, xd1, acc1);
    }
    for (; k < cnt; ++k) {
      int s = __shfl(srcv, k);
      float w0 = __shfl(w0v, k);
      float w1 = __shfl(w1v, k);
      const float* p = xw + (size_t)s * 128 + lane;
      acc0 = fmaf(w0, p[0], acc0);
      acc1 = fmaf(w1, p[64], acc1);
    }
  }
  agg[(size_t)node * 128 + lane] = acc0;
  agg[(size_t)node * 128 + 64 + lane] = acc1;
}

// ---------------- K9: final MLP as tiled GEMM, swizzled LDS ----------------
__global__ __launch_bounds__(256) void final_mlp(
    const float* __restrict__ agg0, const float* __restrict__ agg1,
    const float* __restrict__ agg2, const float* __restrict__ bias0,
    const float* __restrict__ bias1, const float* __restrict__ bias2,
    const float* __restrict__ Wc1, const float* __restrict__ bc1,
    const float* __restrict__ Wc2, const float* __restrict__ bc2,
    float* __restrict__ out, int Nn) {
  __shared__ __align__(16) float xs[TKK][TM];     // swizzled transposed H tile
  __shared__ __align__(16) float4 wsB[TKK][TN/4]; // swizzled Wc1 tile
  __shared__ float red[TM][17];
  const int tid = threadIdx.x;
  const int tx = tid & 15;
  const int ty = tid >> 4;
  const int row0 = blockIdx.x * TM;
  float acc[4][8];
#pragma unroll
  for (int r = 0; r < 4; ++r)
#pragma unroll
    for (int c = 0; c < 8; ++c) acc[r][c] = 0.f;

  const int lr = tid >> 2;
  const int lk = (tid & 3) * 8;
  const int wr = tid >> 3;
  const int bb = (tid & 7) * 4;
  const int xcol = lr ^ (((lk >> 3) & 1) * 16);
  const int p0 = (tx * 2) ^ (2 * ((tx * 2) >> 3));
  const int p1 = (tx * 2 + 1) ^ (2 * ((tx * 2 + 1) >> 3));

  for (int k0 = 0; k0 < 384; k0 += TKK) {
    int row = row0 + lr; if (row >= Nn) row = Nn - 1;
    const int kg = k0 + lk;                  // 8-aligned: single source segment
    const int sel = kg >> 7, q = kg & 127;
    const float* aggp = (sel == 0) ? agg0 : (sel == 1) ? agg1 : agg2;
    const float* bp   = (sel == 0) ? bias0 : (sel == 1) ? bias1 : bias2;
    float4 xa = *(const float4*)(aggp + (size_t)row * 128 + q);
    float4 xb = *(const float4*)(aggp + (size_t)row * 128 + q + 4);
    float4 ba = *(const float4*)(bp + q);
    float4 bbv = *(const float4*)(bp + q + 4);
    xa.x = elu1(xa.x + ba.x); xa.y = elu1(xa.y + ba.y);
    xa.z = elu1(xa.z + ba.z); xa.w = elu1(xa.w + ba.w);
    xb.x = elu1(xb.x + bbv.x); xb.y = elu1(xb.y + bbv.y);
    xb.z = elu1(xb.z + bbv.z); xb.w = elu1(xb.w + bbv.w);
    const float4* wp = (const float4*)(Wc1 + (size_t)(k0 + wr) * TN + bb * 4);
    float4 w0 = wp[0], w1 = wp[1], w2 = wp[2], w3 = wp[3];
    __syncthreads();
    xs[lk + 0][xcol] = xa.x; xs[lk + 1][xcol] = xa.y;
    xs[lk + 2][xcol] = xa.z; xs[lk + 3][xcol] = xa.w;
    xs[lk + 4][xcol] = xb.x; xs[lk + 5][xcol] = xb.y;
    xs[lk + 6][xcol] = xb.z; xs[lk + 7][xcol] = xb.w;
    {
      int b0i = bb + 0; wsB[wr][b0i ^ (2 * (b0i >> 3))] = w0;
      int b1i = bb + 1; wsB[wr][b1i ^ (2 * (b1i >> 3))] = w1;
      int b2i = bb + 2; wsB[wr][b2i ^ (2 * (b2i >> 3))] = w2;
      int b3i = bb + 3; wsB[wr][b3i ^ (2 * (b3i >> 3))] = w3;
    }
    __syncthreads();
#pragma unroll
    for (int k = 0; k < TKK; ++k) {
      const int acol = (ty * 4) ^ (((k >> 3) & 1) * 16);
      float4 a = *(const float4*)&xs[k][acol];
      float4 b0 = wsB[k][p0];
      float4 b1 = wsB[k][p1];
      float av[4] = {a.x, a.y, a.z, a.w};
      float bv[8] = {b0.x, b0.y, b0.z, b0.w, b1.x, b1.y, b1.z, b1.w};
#pragma unroll
      for (int r = 0; r < 4; ++r)
#pragma unroll
        for (int c = 0; c < 8; ++c)
          acc[r][c] = fmaf(av[r], bv[c], acc[r][c]);
    }
  }

  // epilogue: hid = relu(acc + bc1[col]); partial = <hid, Wc2[col]>
  float bcv[8], w2v[8];
#pragma unroll
  for (int c = 0; c < 8; ++c) {
    bcv[c] = bc1[tx * 8 + c];
    w2v[c] = Wc2[tx * 8 + c];
  }
#pragma unroll
  for (int r = 0; r < 4; ++r) {
    float p = 0.f;
#pragma unroll
    for (int c = 0; c < 8; ++c)
      p = fmaf(fmaxf(acc[r][c] + bcv[c], 0.f), w2v[c], p);
    red[ty * 4 + r][tx] = p;
  }
  __syncthreads();
  if (tid < TM) {
    float s = 0.f;
#pragma unroll
    for (int i = 0; i < 16; ++i) s += red[tid][i];
    int n = row0 + tid;
    if (n < Nn) out[n] = s + bc2[0];
  }
}

// ---------------------------------------------------------------------------
extern "C" void kernel_launch(void* const* d_in, const int* in_sizes, int n_in,
                              void* d_out, int out_size, void* d_ws, size_t ws_size,
                              hipStream_t stream) {
  const int Nn = out_size;            // 40000
  const int E0 = in_sizes[1] / 2;
  const int E1 = in_sizes[7] / 2;
  const int E2 = in_sizes[13] / 2;
  const int totE = E0 + E1 + E2;
  const int Nt = 3 * Nn;              // flattened node count

  char* base = (char*)d_ws;
  size_t off = 0;
  auto carve = [&](size_t bytes) -> void* {
    off = (off + 255) & ~(size_t)255;
    void* p = base + off;
    off += bytes;
    return p;
  };
  float* xw    = (float*)carve((size_t)Nn * 128 * 4);       // reused per cat
  float* agg3  = (float*)carve((size_t)Nt * 128 * 4);
  float* a_src3 = (float*)carve((size_t)Nt * 2 * 4);
  float* a_dst3 = (float*)carve((size_t)Nt * 2 * 4);
  int* deg3  = (int*)carve((size_t)Nt * 4);
  int* fill3 = (int*)carve((size_t)Nt * 4);
  int* offs3 = (int*)carve((size_t)(Nt + 1) * 4);
  int* bsum  = (int*)carve(128 * 4);
  int* boff  = (int*)carve(128 * 4);
  int* adj   = (int*)carve((size_t)(totE + Nt) * 4);
  (void)ws_size; (void)n_in;

  const int* ei0 = (const int*)d_in[1];
  const int* ei1 = (const int*)d_in[7];
  const int* ei2 = (const int*)d_in[13];

  const int nscan = (Nt + 1023) / 1024;

  // batched CSR build (independent of features)
  zero3<<<(Nt + 255) / 256, 256, 0, stream>>>(deg3, fill3, Nt);
  hist_b<<<(totE + 255) / 256, 256, 0, stream>>>(ei0, ei1, ei2, E0, E1, E2, Nn, deg3);
  scan_reduce<<<nscan, 1024, 0, stream>>>(deg3, Nt, bsum);
  scan_tops2<<<1, 128, 0, stream>>>(bsum, nscan, boff);
  scan_final<<<nscan, 1024, 0, stream>>>(deg3, Nt, boff, offs3);
  fill_b<<<(totE + Nt + 255) / 256, 256, 0, stream>>>(ei0, ei1, ei2, E0, E1, E2,
                                                      Nn, offs3, fill3, adj);

  for (int cat = 0; cat < 3; ++cat) {
    const float* x   = (const float*)d_in[6 * cat + 0];
    const float* W   = (const float*)d_in[6 * cat + 2];
    const float* ats = (const float*)d_in[6 * cat + 3];
    const float* atd = (const float*)d_in[6 * cat + 4];
    const int K = in_sizes[6 * cat] / Nn;
    float* a_src_c = a_src3 + (size_t)cat * Nn * 2;
    float* a_dst_c = a_dst3 + (size_t)cat * Nn * 2;

    gemm_att<<<(Nn + TM - 1) / TM, 256, 0, stream>>>(
        x, W, ats, atd, xw, a_src_c, a_dst_c, Nn, K);
    aggregate<<<((size_t)Nn * 64 + 255) / 256, 256, 0, stream>>>(
        xw, a_src_c, a_dst_c, offs3 + (size_t)cat * Nn, adj,
        agg3 + (size_t)cat * Nn * 128, Nn);
  }

  final_mlp<<<(Nn + TM - 1) / TM, 256, 0, stream>>>(
      agg3, agg3 + (size_t)Nn * 128, agg3 + (size_t)2 * Nn * 128,
      (const float*)d_in[5], (const float*)d_in[11], (const float*)d_in[17],
      (const float*)d_in[18], (const float*)d_in[19],
      (const float*)d_in[20], (const float*)d_in[21],
      (float*)d_out, Nn);
}